// Round 6
// baseline (376.429 us; speedup 1.0000x reference)
//
#include <hip/hip_runtime.h>
#include <hip/hip_bf16.h>
#include <math.h>

#define B_  2
#define L_  512
#define D_  512
#define H_  16
#define P_  128
#define NL_ 2
#define DH_ 32
#define FF_ 2048
#define NT_ (B_*L_)

typedef __bf16 bf16_t;
typedef bf16_t bf16x8 __attribute__((ext_vector_type(8)));
typedef bf16_t bf16x4 __attribute__((ext_vector_type(4)));
typedef bf16_t bf16x2 __attribute__((ext_vector_type(2)));
typedef float  f32x4  __attribute__((ext_vector_type(4)));

__device__ __forceinline__ float siluf(float x){ return x / (1.f + __expf(-x)); }
__device__ __forceinline__ float geluf(float x){
  const float c = 0.7978845608028654f;  // sqrt(2/pi)
  float x3 = x*x*x;
  return 0.5f*x*(1.f + tanhf(c*(x + 0.044715f*x3)));
}

__device__ __forceinline__ void gload16(const bf16_t* g, bf16_t* l){
  __builtin_amdgcn_global_load_lds(
      (const __attribute__((address_space(1))) unsigned int*)g,
      (__attribute__((address_space(3))) unsigned int*)l, 16, 0, 0);
}

// ---------------- merged preamble: cvtw (9216 blocks) | posemb (1024) | pfb2 (2048) ----------------
#define NB_CVT 9216
#define NB_POS 1024
__global__ __launch_bounds__(256) void k_pre(
      const float* __restrict__ s0, const float* __restrict__ s1,
      const float* __restrict__ s2, const float* __restrict__ s3,
      const float* __restrict__ s4, bf16_t* __restrict__ wdst,
      const float* __restrict__ pos, const float* __restrict__ posw,
      const int* __restrict__ maskp, float* __restrict__ h, float* __restrict__ keepf,
      const float* __restrict__ pair, const float* __restrict__ pfw,
      bf16_t* __restrict__ pfb, float* __restrict__ colm){
  __shared__ float sw[16][128];
  int bid = blockIdx.x;
  int tid = threadIdx.x;
  if (bid < NB_CVT){
    const size_t c0=3145728, c1=4718592, c2=5242880, c3=7340032, c4=9437184;
    size_t e = ((size_t)bid*256 + tid)*4;
    if (e >= c4) return;
    const float* s; size_t off;
    if      (e < c0){ s=s0; off=e; }
    else if (e < c1){ s=s1; off=e-c0; }
    else if (e < c2){ s=s2; off=e-c1; }
    else if (e < c3){ s=s3; off=e-c2; }
    else            { s=s4; off=e-c3; }
    float4 v = *(const float4*)(s + off);
    bf16x4 o; o[0]=(bf16_t)v.x; o[1]=(bf16_t)v.y; o[2]=(bf16_t)v.z; o[3]=(bf16_t)v.w;
    *(bf16x4*)(wdst + e) = o;
    return;
  }
  if (bid < NB_CVT + NB_POS){
    int n = bid - NB_CVT;                     // b*L + l
    float kf = (maskp[n] != 0) ? 0.f : 1.f;   // True = pad
    if (tid == 0) keepf[n] = kf;
    float p0 = pos[n*3+0], p1 = pos[n*3+1], p2 = pos[n*3+2];
    for (int d = tid; d < D_; d += 256){
      float v = p0*posw[d*3+0] + p1*posw[d*3+1] + p2*posw[d*3+2];
      h[(size_t)n*D_ + d] = kf*v;
    }
    return;
  }
  // pair bias fused with col-mean
  int blk = bid - NB_CVT - NB_POS;
  int mc = blk & 1;            // m half (256 each)
  int n  = blk >> 1;           // b*L + l
  int b = n >> 9, l = n & 511;
  {
    float4* swv = (float4*)&sw[0][0];
    const float4* wv = (const float4*)pfw;
    swv[tid] = wv[tid];
    swv[tid + 256] = wv[tid + 256];
  }
  __syncthreads();
  int m = mc*256 + tid;
  const float* rowp = pair + (((size_t)n)*512 + m)*128;
  float acc[16] = {};
  #pragma unroll 4
  for (int pc = 0; pc < 32; ++pc){
    float4 v = ((const float4*)rowp)[pc];
    v.x = siluf(v.x); v.y = siluf(v.y); v.z = siluf(v.z); v.w = siluf(v.w);
    #pragma unroll
    for (int hh = 0; hh < 16; ++hh){
      float4 wv = *(const float4*)&sw[hh][pc*4];   // wave-uniform broadcast
      acc[hh] += v.x*wv.x + v.y*wv.y + v.z*wv.z + v.w*wv.w;
    }
  }
  float mean = 0.f;
  #pragma unroll
  for (int hh = 0; hh < 16; ++hh) mean += acc[hh];
  colm[((size_t)n)*512 + m] = mean * (1.f/16.f);
  #pragma unroll
  for (int hh = 0; hh < 16; ++hh)
    pfb[(((size_t)(b*16 + hh))*512 + l)*512 + m] = (bf16_t)acc[hh];
}

// ---------------- top-3 rows per column + pair2node MLP + cond = silu(x + f2n) ----------------
__global__ __launch_bounds__(128) void k_topk_f2n(const float* __restrict__ colm,
      const float* __restrict__ pair, const float* __restrict__ keepf,
      const float* __restrict__ w1, const float* __restrict__ w2,
      const float* __restrict__ xin, bf16_t* __restrict__ cond){
  int n = blockIdx.x; int b = n >> 9, m = n & 511;
  __shared__ int sidx[3];
  __shared__ float f2n_s[128];
  __shared__ float u_s[128];
  int tid = threadIdx.x;
  if (tid < 64){
    const float* colbase = colm + ((size_t)b*512)*512 + m;   // stride 512 over l
    float v[8];
    #pragma unroll
    for (int i = 0; i < 8; ++i) v[i] = colbase[(size_t)(tid + 64*i)*512];
    int c0 = -1, c1 = -1;
    for (int r = 0; r < 3; ++r){
      float bv = -INFINITY; int bi = 1 << 30;
      #pragma unroll
      for (int i = 0; i < 8; ++i){
        int idx = tid + 64*i;
        bool excl = (idx == c0) || (idx == c1);
        float val = v[i];
        if (!excl && (val > bv || (val == bv && idx < bi))){ bv = val; bi = idx; }
      }
      for (int o = 32; o > 0; o >>= 1){
        float ov = __shfl_down(bv, o);
        int   oi = __shfl_down(bi, o);
        if (ov > bv || (ov == bv && oi < bi)){ bv = ov; bi = oi; }
      }
      bi = __shfl(bi, 0);
      if (tid == 0) sidx[r] = bi;
      if (r == 0) c0 = bi; else c1 = bi;
    }
  }
  __syncthreads();
  int i0 = sidx[0], i1 = sidx[1], i2 = sidx[2];
  float kc = keepf[n];
  float k0 = keepf[b*512 + i0], k1 = keepf[b*512 + i1], k2 = keepf[b*512 + i2];
  {
    int p = tid;
    float s = k0*pair[(((size_t)(b*512 + i0))*512 + m)*128 + p]
            + k1*pair[(((size_t)(b*512 + i1))*512 + m)*128 + p]
            + k2*pair[(((size_t)(b*512 + i2))*512 + m)*128 + p];
    f2n_s[p] = s * kc * (1.f/3.f);
  }
  __syncthreads();
  {
    int j = tid;
    const float* wr = w1 + (size_t)j*128;
    float acc = 0.f;
    #pragma unroll 8
    for (int p = 0; p < 128; ++p) acc += f2n_s[p]*wr[p];
    u_s[j] = siluf(acc);
  }
  __syncthreads();
  for (int d = tid; d < 512; d += 128){
    const float* wr = w2 + (size_t)d*128;
    float acc = 0.f;
    #pragma unroll 8
    for (int p = 0; p < 128; ++p) acc += u_s[p]*wr[p];
    float xv = xin[((size_t)(m*2 + b))*512 + d];     // x is [L,B,D]
    cond[(size_t)n*512 + d] = (bf16_t)siluf(xv + acc);
  }
}

// ---------------- LayerNorm(h [+ te]) * (1+sc) + sh -> bf16 ----------------
__global__ __launch_bounds__(128) void k_lnmod2(const float* __restrict__ hbase,
      const float* __restrict__ te, const float* __restrict__ mod,
      bf16_t* __restrict__ out, int sh_off, int sc_off, int mstride){
  int n = blockIdx.x; int b = n >> 9;
  int tid = threadIdx.x;
  float4 v = ((const float4*)(hbase + (size_t)n*512))[tid];
  if (te){
    float4 t = ((const float4*)(te + (size_t)b*512))[tid];
    v.x += t.x; v.y += t.y; v.z += t.z; v.w += t.w;
  }
  float s = v.x + v.y + v.z + v.w;
  float q = v.x*v.x + v.y*v.y + v.z*v.z + v.w*v.w;
  #pragma unroll
  for (int o = 1; o < 64; o <<= 1){ s += __shfl_xor(s, o); q += __shfl_xor(q, o); }
  __shared__ float s2[2], q2[2];
  if ((tid & 63) == 0){ s2[tid >> 6] = s; q2[tid >> 6] = q; }
  __syncthreads();
  float S = s2[0] + s2[1], Q = q2[0] + q2[1];
  float mean = S * (1.f/512.f);
  float var  = Q * (1.f/512.f) - mean*mean;
  float rstd = rsqrtf(var + 1e-5f);
  const float* mrow = mod + (size_t)n*mstride;
  float4 sc = *(const float4*)(mrow + sc_off + tid*4);
  float4 sh = *(const float4*)(mrow + sh_off + tid*4);
  bf16x4 rv;
  rv[0] = (bf16_t)((v.x - mean)*rstd*(1.f + sc.x) + sh.x);
  rv[1] = (bf16_t)((v.y - mean)*rstd*(1.f + sc.y) + sh.y);
  rv[2] = (bf16_t)((v.z - mean)*rstd*(1.f + sc.z) + sh.z);
  rv[3] = (bf16_t)((v.w - mean)*rstd*(1.f + sc.w) + sh.w);
  *(bf16x4*)(out + (size_t)n*512 + tid*4) = rv;
}

// ---------------- bf16 MFMA GEMM, double-buffered global_load_lds staging ----------------
// C[M,N] = epi(A[M,K] @ Bw[N,K]^T + bias)
// epi: 0 plain f32 | 1 proj: outf = res + te + gate*v | 2 gelu->bf16
//      3 qkv->bf16 (+vT for V cols) | 4 mlp2: outf = res + gate*v
// 4 waves in a 2x2 quadrant layout; wave covers (BM/2)x(BN/2) via FMxFN 16x16 frags.
template<int BM, int BN>
__global__ __launch_bounds__(256) void k_gemm_bf(const bf16_t* __restrict__ A,
      const bf16_t* __restrict__ Bw, const float* __restrict__ bias,
      int M, int N, int K, int epi,
      float* __restrict__ outf, bf16_t* __restrict__ outb,
      const float* __restrict__ res, const float* __restrict__ gate, int gate_ld,
      const float* __restrict__ te, bf16_t* __restrict__ vT){
  const int FM = BM/32, FN = BN/32;
  const int CA = BM/32, CB = BN/32;      // 16B staging chunks per thread
  __shared__ __align__(16) bf16_t As[2][BM*64];
  __shared__ __align__(16) bf16_t Bs[2][BN*64];
  int tid = threadIdx.x;
  int m0 = blockIdx.y*BM, n0 = blockIdx.x*BN;
  int lane = tid & 63, wid = tid >> 6;
  int wr = wid >> 1, wc = wid & 1;
  int frow = lane & 15, g = lane >> 4;
  f32x4 acc[FM][FN] = {};

  auto stage = [&](int buf, int k0){
    int e = tid;
    #pragma unroll
    for (int i = 0; i < CA; ++i, e += 256){
      int row = e >> 3, cb = e & 7;
      gload16(A + (size_t)(m0+row)*K + k0 + ((cb ^ (row&7))<<3), &As[buf][e*8]);
    }
    e = tid;
    #pragma unroll
    for (int i = 0; i < CB; ++i, e += 256){
      int row = e >> 3, cb = e & 7;
      gload16(Bw + (size_t)(n0+row)*K + k0 + ((cb ^ (row&7))<<3), &Bs[buf][e*8]);
    }
  };
  auto compute = [&](int buf){
    #pragma unroll
    for (int ks = 0; ks < 2; ++ks){
      bf16x8 af[FM], bfv[FN];
      #pragma unroll
      for (int fm = 0; fm < FM; ++fm){
        int ar = wr*(BM/2) + fm*16 + frow;
        af[fm] = *(const bf16x8*)&As[buf][ar*64 + (((ks*4+g) ^ (ar&7))<<3)];
      }
      #pragma unroll
      for (int fn = 0; fn < FN; ++fn){
        int br = wc*(BN/2) + fn*16 + frow;
        bfv[fn] = *(const bf16x8*)&Bs[buf][br*64 + (((ks*4+g) ^ (br&7))<<3)];
      }
      #pragma unroll
      for (int fm = 0; fm < FM; ++fm)
        #pragma unroll
        for (int fn = 0; fn < FN; ++fn)
          acc[fm][fn] = __builtin_amdgcn_mfma_f32_16x16x32_bf16(af[fm], bfv[fn], acc[fm][fn], 0,0,0);
    }
  };

  stage(0, 0);
  __syncthreads();
  int cur = 0;
  for (int k0 = 64; k0 < K; k0 += 64){
    stage(cur^1, k0);          // prefetch next tile (loads fly during MFMA)
    compute(cur);
    __syncthreads();           // drains prefetch + protects LDS reuse
    cur ^= 1;
  }
  compute(cur);

  #pragma unroll
  for (int fm = 0; fm < FM; ++fm){
    #pragma unroll
    for (int fn = 0; fn < FN; ++fn){
      int n = n0 + wc*(BN/2) + fn*16 + frow;
      float bb = bias[n];
      int row0 = m0 + wr*(BM/2) + fm*16 + g*4;
      if (epi == 3 && n >= 1024){
        int hh = (n-1024)>>5, dh = (n-1024)&31;
        int b = row0>>9, ll = row0&511;
        bf16x4 pv;
        #pragma unroll
        for (int i = 0; i < 4; ++i){
          float v = acc[fm][fn][i] + bb;
          outb[(size_t)(row0+i)*N + n] = (bf16_t)v;
          pv[i] = (bf16_t)v;
        }
        *(bf16x4*)&vT[(((size_t)(b*16+hh))*32 + dh)*512 + ll] = pv;
      } else {
        #pragma unroll
        for (int i = 0; i < 4; ++i){
          int row = row0 + i;
          float v = acc[fm][fn][i] + bb;
          if (epi == 1){
            v = res[(size_t)row*N + n] + te[(row>>9)*D_ + n] + gate[(size_t)row*gate_ld + n]*v;
            outf[(size_t)row*N + n] = v;
          } else if (epi == 2){
            outb[(size_t)row*N + n] = (bf16_t)geluf(v);
          } else if (epi == 3){
            outb[(size_t)row*N + n] = (bf16_t)v;
          } else if (epi == 4){
            v = res[(size_t)row*N + n] + gate[(size_t)row*gate_ld + n]*v;
            outf[(size_t)row*N + n] = v;
          } else {
            outf[(size_t)row*N + n] = v;
          }
        }
      }
    }
  }
}

// ---------------- MFMA attention: block = (b,h,16-row q-tile) ----------------
__global__ __launch_bounds__(256) void k_attn2(const bf16_t* __restrict__ qkv,
      const bf16_t* __restrict__ vT, const bf16_t* __restrict__ pfb,
      const float* __restrict__ keepf, bf16_t* __restrict__ obuf){
  __shared__ float ss[16][516];
  __shared__ float opart[4][16][33];
  __shared__ float inv_s[16];
  int blk = blockIdx.x;
  int qt = blk & 31;
  int bh = blk >> 5;
  int b = bh >> 4, h = bh & 15;
  int r0 = qt*16;
  int tid = threadIdx.x;
  int lane = tid & 63, w = tid >> 6;
  int frow = lane & 15, g = lane >> 4;
  const float scale = 0.17677669529663687f;  // 1/sqrt(32)
  bf16x8 qf = *(const bf16x8*)(qkv + (size_t)(b*512 + r0 + frow)*1536 + h*32 + g*8);
  // phase 1: S = QK^T*scale + pfb, masked; wave w covers k in [w*128, w*128+128)
  #pragma unroll
  for (int t = 0; t < 8; ++t){
    int kc = w*128 + t*16;
    bf16x8 kf = *(const bf16x8*)(qkv + (size_t)(b*512 + kc + frow)*1536 + 512 + h*32 + g*8);
    f32x4 s4 = {};
    s4 = __builtin_amdgcn_mfma_f32_16x16x32_bf16(qf, kf, s4, 0,0,0);
    int tok = kc + frow;
    float kp = keepf[b*512 + tok];
    const bf16_t* pf = pfb + ((size_t)bh*512 + r0 + g*4)*512 + tok;
    #pragma unroll
    for (int i = 0; i < 4; ++i){
      float sv = s4[i]*scale + (float)pf[(size_t)i*512];
      sv = (kp == 0.f) ? -1e9f : sv;
      ss[g*4+i][tok] = sv;
    }
  }
  __syncthreads();
  // softmax (unnormalized e kept in ss; inv_s per row)
  {
    int r = tid >> 4, mo = tid & 15;
    float mx = -INFINITY;
    #pragma unroll 8
    for (int t2 = 0; t2 < 32; ++t2) mx = fmaxf(mx, ss[r][mo + 16*t2]);
    #pragma unroll
    for (int o = 1; o < 16; o <<= 1) mx = fmaxf(mx, __shfl_xor(mx, o));
    float sum = 0.f;
    #pragma unroll 8
    for (int t2 = 0; t2 < 32; ++t2){
      int m = mo + 16*t2;
      float e = __expf(ss[r][m] - mx);
      ss[r][m] = e;
      sum += e;
    }
    #pragma unroll
    for (int o = 1; o < 16; o <<= 1) sum += __shfl_xor(sum, o);
    if (mo == 0) inv_s[r] = 1.f/sum;
  }
  __syncthreads();
  // phase 2: O_partial = P[16, w-range] @ V[w-range, 32]
  f32x4 oacc[2] = {};
  #pragma unroll
  for (int t = 0; t < 4; ++t){
    int kc = w*128 + t*32;
    float4 p0 = *(const float4*)&ss[frow][kc + g*8];
    float4 p1 = *(const float4*)&ss[frow][kc + g*8 + 4];
    bf16x8 pfr;
    pfr[0]=(bf16_t)p0.x; pfr[1]=(bf16_t)p0.y; pfr[2]=(bf16_t)p0.z; pfr[3]=(bf16_t)p0.w;
    pfr[4]=(bf16_t)p1.x; pfr[5]=(bf16_t)p1.y; pfr[6]=(bf16_t)p1.z; pfr[7]=(bf16_t)p1.w;
    #pragma unroll
    for (int fn = 0; fn < 2; ++fn){
      bf16x8 vf = *(const bf16x8*)(vT + ((size_t)bh*32 + fn*16 + frow)*512 + kc + g*8);
      oacc[fn] = __builtin_amdgcn_mfma_f32_16x16x32_bf16(pfr, vf, oacc[fn], 0,0,0);
    }
  }
  #pragma unroll
  for (int fn = 0; fn < 2; ++fn)
    #pragma unroll
    for (int i = 0; i < 4; ++i)
      opart[w][g*4+i][fn*16+frow] = oacc[fn][i];
  __syncthreads();
  // reduce over waves + normalize + write bf16
  {
    int q = tid >> 4, dh = (tid & 15)*2;
    float o0 = 0.f, o1 = 0.f;
    #pragma unroll
    for (int ww = 0; ww < 4; ++ww){ o0 += opart[ww][q][dh]; o1 += opart[ww][q][dh+1]; }
    float inv = inv_s[q];
    bf16x2 ov; ov[0] = (bf16_t)(o0*inv); ov[1] = (bf16_t)(o1*inv);
    *(bf16x2*)(obuf + (size_t)(b*512 + r0 + q)*512 + h*32 + dh) = ov;
  }
}

extern "C" void kernel_launch(void* const* d_in, const int* in_sizes, int n_in,
                              void* d_out, int out_size, void* d_ws, size_t ws_size,
                              hipStream_t stream){
  (void)in_sizes; (void)n_in; (void)out_size; (void)ws_size;
  const float* x        = (const float*)d_in[0];
  const float* pos      = (const float*)d_in[1];
  const float* time_emb = (const float*)d_in[2];
  const float* pair     = (const float*)d_in[3];
  const float* pos_w    = (const float*)d_in[4];
  const float* pfb_w    = (const float*)d_in[5];
  const float* p2n_w1   = (const float*)d_in[6];
  const float* p2n_w2   = (const float*)d_in[7];
  const float* adaln_w  = (const float*)d_in[8];
  const float* adaln_b  = (const float*)d_in[9];
  const float* qkv_w    = (const float*)d_in[10];
  const float* qkv_b    = (const float*)d_in[11];
  const float* proj_w   = (const float*)d_in[12];
  const float* proj_b   = (const float*)d_in[13];
  const float* mlp_w1   = (const float*)d_in[14];
  const float* mlp_b1   = (const float*)d_in[15];
  const float* mlp_w2   = (const float*)d_in[16];
  const float* mlp_b2   = (const float*)d_in[17];
  const int*   maskp    = (const int*)d_in[18];

  float* W = (float*)d_ws;
  size_t off = 0;
  auto alloc = [&](size_t nfw){ float* p = W + off; off += nfw; return p; };
  float*  h     = alloc(524288);
  float*  hin2  = alloc(524288);
  float*  modb  = alloc(6291456);            // [1024][6144] both layers
  float*  colm  = alloc(524288);
  float*  keepf = alloc(1024);
  bf16_t* pfbb  = (bf16_t*)alloc(4194304);   // 8,388,608 bf16
  bf16_t* condb = (bf16_t*)alloc(262144);    // 524,288 bf16
  bf16_t* abuf  = (bf16_t*)alloc(262144);    // 524,288 bf16
  bf16_t* qkvb  = (bf16_t*)alloc(786432);    // 1,572,864 bf16
  bf16_t* vTb   = (bf16_t*)alloc(262144);    // 524,288 bf16
  bf16_t* midb  = (bf16_t*)alloc(1048576);   // 2,097,152 bf16
  bf16_t* obuf  = (bf16_t*)alloc(262144);    // 524,288 bf16
  bf16_t* wB    = (bf16_t*)alloc(4718592);   // 9,437,184 bf16
  bf16_t* wA  = wB;                 // [2][3072][512]
  bf16_t* wQ  = wB + 3145728;
  bf16_t* wP  = wB + 4718592;
  bf16_t* wM1 = wB + 5242880;
  bf16_t* wM2 = wB + 7340032;

  // merged preamble: weight-cvt | posemb | pair-bias+colmean
  k_pre<<<NB_CVT + NB_POS + NT_*2, 256, 0, stream>>>(
      adaln_w, qkv_w, proj_w, mlp_w1, mlp_w2, wB,
      pos, pos_w, maskp, h, keepf,
      pair, pfb_w, pfbb, colm);
  k_topk_f2n<<<NT_, 128, 0, stream>>>(colm, pair, keepf, p2n_w1, p2n_w2, x, condb);
  // batched adaLN for BOTH layers: modb[1024][6144] = cond @ [2·3072,512]^T + b  (128x128 tiles)
  k_gemm_bf<128,128><<<dim3(48,8), 256, 0, stream>>>(condb, wA, adaln_b,
      NT_, 6144, 512, 0, modb, nullptr, nullptr, nullptr, 0, nullptr, nullptr);

  for (int l = 0; l < NL_; ++l){
    const float* modl = modb + (size_t)l*3072;
    // a = LN(h+te)*(1+sc_a)+sh_a -> bf16
    k_lnmod2<<<NT_, 128, 0, stream>>>(h, time_emb, modl, abuf, 0, 512, 6144);
    // qkv -> bf16 (+ vT)   64x128 tiles
    k_gemm_bf<64,128><<<dim3(12,16), 256, 0, stream>>>(abuf, wQ + (size_t)l*1536*512,
        qkv_b + (size_t)l*1536, NT_, 1536, 512, 3, nullptr, qkvb, nullptr, nullptr, 0, nullptr, vTb);
    k_attn2<<<B_*H_*32, 256, 0, stream>>>(qkvb, vTb, pfbb, keepf, obuf);
    // hin2 = (h+te) + g_a * (o@proj^T + b)   64x32 tiles
    k_gemm_bf<64,32><<<dim3(16,16), 256, 0, stream>>>(obuf, wP + (size_t)l*512*512,
        proj_b + (size_t)l*512, NT_, 512, 512, 1, hin2, nullptr, h,
        (const float*)(modl + 2*512), 6144, time_emb, nullptr);
    k_lnmod2<<<NT_, 128, 0, stream>>>(hin2, nullptr, modl, abuf, 3*512, 4*512, 6144);
    // mlp1 gelu -> bf16   64x128 tiles
    k_gemm_bf<64,128><<<dim3(16,16), 256, 0, stream>>>(abuf, wM1 + (size_t)l*2048*512,
        mlp_b1 + (size_t)l*2048, NT_, 2048, 512, 2, nullptr, midb, nullptr, nullptr, 0, nullptr, nullptr);
    // h_out = hin2 + g_m * (mid@mlp2^T + b)   64x32 tiles
    float* hout = (l == NL_-1) ? (float*)d_out : h;
    k_gemm_bf<64,32><<<dim3(16,16), 256, 0, stream>>>(midb, wM2 + (size_t)l*512*2048,
        mlp_b2 + (size_t)l*512, NT_, 512, 2048, 4, hout, nullptr, hin2,
        (const float*)(modl + 5*512), 6144, nullptr, nullptr);
  }
}

// Round 7
// 353.161 us; speedup vs baseline: 1.0659x; 1.0659x over previous
//
#include <hip/hip_runtime.h>
#include <hip/hip_bf16.h>
#include <math.h>

#define B_  2
#define L_  512
#define D_  512
#define H_  16
#define P_  128
#define NL_ 2
#define DH_ 32
#define FF_ 2048
#define NT_ (B_*L_)

typedef __bf16 bf16_t;
typedef bf16_t bf16x8 __attribute__((ext_vector_type(8)));
typedef bf16_t bf16x4 __attribute__((ext_vector_type(4)));
typedef bf16_t bf16x2 __attribute__((ext_vector_type(2)));
typedef float  f32x4  __attribute__((ext_vector_type(4)));

__device__ __forceinline__ float siluf(float x){ return x / (1.f + __expf(-x)); }
__device__ __forceinline__ float geluf(float x){
  const float c = 0.7978845608028654f;  // sqrt(2/pi)
  float x3 = x*x*x;
  return 0.5f*x*(1.f + tanhf(c*(x + 0.044715f*x3)));
}

__device__ __forceinline__ void gload16(const bf16_t* g, bf16_t* l){
  __builtin_amdgcn_global_load_lds(
      (const __attribute__((address_space(1))) unsigned int*)g,
      (__attribute__((address_space(3))) unsigned int*)l, 16, 0, 0);
}

// ---------------- merged preamble: cvtw (9216 blocks) | posemb (1024) | pfb2 (2048) ----------------
#define NB_CVT 9216
#define NB_POS 1024
__global__ __launch_bounds__(256) void k_pre(
      const float* __restrict__ s0, const float* __restrict__ s1,
      const float* __restrict__ s2, const float* __restrict__ s3,
      const float* __restrict__ s4, bf16_t* __restrict__ wdst,
      const float* __restrict__ pos, const float* __restrict__ posw,
      const int* __restrict__ maskp, float* __restrict__ h, float* __restrict__ keepf,
      const float* __restrict__ pair, const float* __restrict__ pfw,
      bf16_t* __restrict__ pfb, float* __restrict__ colm){
  __shared__ float sw[16][128];
  int bid = blockIdx.x;
  int tid = threadIdx.x;
  if (bid < NB_CVT){
    const size_t c0=3145728, c1=4718592, c2=5242880, c3=7340032, c4=9437184;
    size_t e = ((size_t)bid*256 + tid)*4;
    if (e >= c4) return;
    const float* s; size_t off;
    if      (e < c0){ s=s0; off=e; }
    else if (e < c1){ s=s1; off=e-c0; }
    else if (e < c2){ s=s2; off=e-c1; }
    else if (e < c3){ s=s3; off=e-c2; }
    else            { s=s4; off=e-c3; }
    float4 v = *(const float4*)(s + off);
    bf16x4 o; o[0]=(bf16_t)v.x; o[1]=(bf16_t)v.y; o[2]=(bf16_t)v.z; o[3]=(bf16_t)v.w;
    *(bf16x4*)(wdst + e) = o;
    return;
  }
  if (bid < NB_CVT + NB_POS){
    int n = bid - NB_CVT;                     // b*L + l
    float kf = (maskp[n] != 0) ? 0.f : 1.f;   // True = pad
    if (tid == 0) keepf[n] = kf;
    float p0 = pos[n*3+0], p1 = pos[n*3+1], p2 = pos[n*3+2];
    for (int d = tid; d < D_; d += 256){
      float v = p0*posw[d*3+0] + p1*posw[d*3+1] + p2*posw[d*3+2];
      h[(size_t)n*D_ + d] = kf*v;
    }
    return;
  }
  // pair bias fused with col-mean
  int blk = bid - NB_CVT - NB_POS;
  int mc = blk & 1;            // m half (256 each)
  int n  = blk >> 1;           // b*L + l
  int b = n >> 9, l = n & 511;
  {
    float4* swv = (float4*)&sw[0][0];
    const float4* wv = (const float4*)pfw;
    swv[tid] = wv[tid];
    swv[tid + 256] = wv[tid + 256];
  }
  __syncthreads();
  int m = mc*256 + tid;
  const float* rowp = pair + (((size_t)n)*512 + m)*128;
  float acc[16] = {};
  #pragma unroll 4
  for (int pc = 0; pc < 32; ++pc){
    float4 v = ((const float4*)rowp)[pc];
    v.x = siluf(v.x); v.y = siluf(v.y); v.z = siluf(v.z); v.w = siluf(v.w);
    #pragma unroll
    for (int hh = 0; hh < 16; ++hh){
      float4 wv = *(const float4*)&sw[hh][pc*4];   // wave-uniform broadcast
      acc[hh] += v.x*wv.x + v.y*wv.y + v.z*wv.z + v.w*wv.w;
    }
  }
  float mean = 0.f;
  #pragma unroll
  for (int hh = 0; hh < 16; ++hh) mean += acc[hh];
  colm[((size_t)n)*512 + m] = mean * (1.f/16.f);
  #pragma unroll
  for (int hh = 0; hh < 16; ++hh)
    pfb[(((size_t)(b*16 + hh))*512 + l)*512 + m] = (bf16_t)acc[hh];
}

// ---------------- top-3 rows per column + pair2node MLP + cond = silu(x + f2n) ----------------
__global__ __launch_bounds__(128) void k_topk_f2n(const float* __restrict__ colm,
      const float* __restrict__ pair, const float* __restrict__ keepf,
      const float* __restrict__ w1, const float* __restrict__ w2,
      const float* __restrict__ xin, bf16_t* __restrict__ cond){
  int n = blockIdx.x; int b = n >> 9, m = n & 511;
  __shared__ int sidx[3];
  __shared__ float f2n_s[128];
  __shared__ float u_s[128];
  int tid = threadIdx.x;
  if (tid < 64){
    const float* colbase = colm + ((size_t)b*512)*512 + m;   // stride 512 over l
    float v[8];
    #pragma unroll
    for (int i = 0; i < 8; ++i) v[i] = colbase[(size_t)(tid + 64*i)*512];
    int c0 = -1, c1 = -1;
    for (int r = 0; r < 3; ++r){
      float bv = -INFINITY; int bi = 1 << 30;
      #pragma unroll
      for (int i = 0; i < 8; ++i){
        int idx = tid + 64*i;
        bool excl = (idx == c0) || (idx == c1);
        float val = v[i];
        if (!excl && (val > bv || (val == bv && idx < bi))){ bv = val; bi = idx; }
      }
      for (int o = 32; o > 0; o >>= 1){
        float ov = __shfl_down(bv, o);
        int   oi = __shfl_down(bi, o);
        if (ov > bv || (ov == bv && oi < bi)){ bv = ov; bi = oi; }
      }
      bi = __shfl(bi, 0);
      if (tid == 0) sidx[r] = bi;
      if (r == 0) c0 = bi; else c1 = bi;
    }
  }
  __syncthreads();
  int i0 = sidx[0], i1 = sidx[1], i2 = sidx[2];
  float kc = keepf[n];
  float k0 = keepf[b*512 + i0], k1 = keepf[b*512 + i1], k2 = keepf[b*512 + i2];
  {
    int p = tid;
    float s = k0*pair[(((size_t)(b*512 + i0))*512 + m)*128 + p]
            + k1*pair[(((size_t)(b*512 + i1))*512 + m)*128 + p]
            + k2*pair[(((size_t)(b*512 + i2))*512 + m)*128 + p];
    f2n_s[p] = s * kc * (1.f/3.f);
  }
  __syncthreads();
  {
    int j = tid;
    const float* wr = w1 + (size_t)j*128;
    float acc = 0.f;
    #pragma unroll 8
    for (int p = 0; p < 128; ++p) acc += f2n_s[p]*wr[p];
    u_s[j] = siluf(acc);
  }
  __syncthreads();
  for (int d = tid; d < 512; d += 128){
    const float* wr = w2 + (size_t)d*128;
    float acc = 0.f;
    #pragma unroll 8
    for (int p = 0; p < 128; ++p) acc += u_s[p]*wr[p];
    float xv = xin[((size_t)(m*2 + b))*512 + d];     // x is [L,B,D]
    cond[(size_t)n*512 + d] = (bf16_t)siluf(xv + acc);
  }
}

// ---------------- LayerNorm(h [+ te]) * (1+sc) + sh -> bf16  (mod in bf16) ----------------
__global__ __launch_bounds__(128) void k_lnmod2(const float* __restrict__ hbase,
      const float* __restrict__ te, const bf16_t* __restrict__ mod,
      bf16_t* __restrict__ out, int sh_off, int sc_off, int mstride){
  int n = blockIdx.x; int b = n >> 9;
  int tid = threadIdx.x;
  float4 v = ((const float4*)(hbase + (size_t)n*512))[tid];
  if (te){
    float4 t = ((const float4*)(te + (size_t)b*512))[tid];
    v.x += t.x; v.y += t.y; v.z += t.z; v.w += t.w;
  }
  float s = v.x + v.y + v.z + v.w;
  float q = v.x*v.x + v.y*v.y + v.z*v.z + v.w*v.w;
  #pragma unroll
  for (int o = 1; o < 64; o <<= 1){ s += __shfl_xor(s, o); q += __shfl_xor(q, o); }
  __shared__ float s2[2], q2[2];
  if ((tid & 63) == 0){ s2[tid >> 6] = s; q2[tid >> 6] = q; }
  __syncthreads();
  float S = s2[0] + s2[1], Q = q2[0] + q2[1];
  float mean = S * (1.f/512.f);
  float var  = Q * (1.f/512.f) - mean*mean;
  float rstd = rsqrtf(var + 1e-5f);
  const bf16_t* mrow = mod + (size_t)n*mstride;
  bf16x4 sc = *(const bf16x4*)(mrow + sc_off + tid*4);
  bf16x4 sh = *(const bf16x4*)(mrow + sh_off + tid*4);
  bf16x4 rv;
  rv[0] = (bf16_t)((v.x - mean)*rstd*(1.f + (float)sc[0]) + (float)sh[0]);
  rv[1] = (bf16_t)((v.y - mean)*rstd*(1.f + (float)sc[1]) + (float)sh[1]);
  rv[2] = (bf16_t)((v.z - mean)*rstd*(1.f + (float)sc[2]) + (float)sh[2]);
  rv[3] = (bf16_t)((v.w - mean)*rstd*(1.f + (float)sc[3]) + (float)sh[3]);
  *(bf16x4*)(out + (size_t)n*512 + tid*4) = rv;
}

// ---------------- bf16 MFMA GEMM, double-buffered global_load_lds staging ----------------
// C[M,N] = epi(A[M,K] @ Bw[N,K]^T + bias)
// epi: 0 plain -> bf16 | 1 proj: outf = res + te + gate*v | 2 gelu->bf16
//      3 qkv->bf16 (+vT for V cols) | 4 mlp2: outf = res + gate*v
// gate is bf16 (modb); res/te are f32.
template<int BM, int BN>
__global__ __launch_bounds__(256) void k_gemm_bf(const bf16_t* __restrict__ A,
      const bf16_t* __restrict__ Bw, const float* __restrict__ bias,
      int M, int N, int K, int epi,
      float* __restrict__ outf, bf16_t* __restrict__ outb,
      const float* __restrict__ res, const bf16_t* __restrict__ gate, int gate_ld,
      const float* __restrict__ te, bf16_t* __restrict__ vT){
  const int FM = BM/32, FN = BN/32;
  const int CA = BM/32, CB = BN/32;      // 16B staging chunks per thread
  __shared__ __align__(16) bf16_t As[2][BM*64];
  __shared__ __align__(16) bf16_t Bs[2][BN*64];
  int tid = threadIdx.x;
  int m0 = blockIdx.y*BM, n0 = blockIdx.x*BN;
  int lane = tid & 63, wid = tid >> 6;
  int wr = wid >> 1, wc = wid & 1;
  int frow = lane & 15, g = lane >> 4;
  f32x4 acc[FM][FN] = {};

  auto stage = [&](int buf, int k0){
    int e = tid;
    #pragma unroll
    for (int i = 0; i < CA; ++i, e += 256){
      int row = e >> 3, cb = e & 7;
      gload16(A + (size_t)(m0+row)*K + k0 + ((cb ^ (row&7))<<3), &As[buf][e*8]);
    }
    e = tid;
    #pragma unroll
    for (int i = 0; i < CB; ++i, e += 256){
      int row = e >> 3, cb = e & 7;
      gload16(Bw + (size_t)(n0+row)*K + k0 + ((cb ^ (row&7))<<3), &Bs[buf][e*8]);
    }
  };
  auto compute = [&](int buf){
    #pragma unroll
    for (int ks = 0; ks < 2; ++ks){
      bf16x8 af[FM], bfv[FN];
      #pragma unroll
      for (int fm = 0; fm < FM; ++fm){
        int ar = wr*(BM/2) + fm*16 + frow;
        af[fm] = *(const bf16x8*)&As[buf][ar*64 + (((ks*4+g) ^ (ar&7))<<3)];
      }
      #pragma unroll
      for (int fn = 0; fn < FN; ++fn){
        int br = wc*(BN/2) + fn*16 + frow;
        bfv[fn] = *(const bf16x8*)&Bs[buf][br*64 + (((ks*4+g) ^ (br&7))<<3)];
      }
      #pragma unroll
      for (int fm = 0; fm < FM; ++fm)
        #pragma unroll
        for (int fn = 0; fn < FN; ++fn)
          acc[fm][fn] = __builtin_amdgcn_mfma_f32_16x16x32_bf16(af[fm], bfv[fn], acc[fm][fn], 0,0,0);
    }
  };

  stage(0, 0);
  __syncthreads();
  int cur = 0;
  for (int k0 = 64; k0 < K; k0 += 64){
    stage(cur^1, k0);          // prefetch next tile (loads fly during MFMA)
    compute(cur);
    __syncthreads();           // drains prefetch + protects LDS reuse
    cur ^= 1;
  }
  compute(cur);

  #pragma unroll
  for (int fm = 0; fm < FM; ++fm){
    #pragma unroll
    for (int fn = 0; fn < FN; ++fn){
      int n = n0 + wc*(BN/2) + fn*16 + frow;
      float bb = bias[n];
      int row0 = m0 + wr*(BM/2) + fm*16 + g*4;
      if (epi == 3 && n >= 1024){
        int hh = (n-1024)>>5, dh = (n-1024)&31;
        int b = row0>>9, ll = row0&511;
        bf16x4 pv;
        #pragma unroll
        for (int i = 0; i < 4; ++i){
          float v = acc[fm][fn][i] + bb;
          outb[(size_t)(row0+i)*N + n] = (bf16_t)v;
          pv[i] = (bf16_t)v;
        }
        *(bf16x4*)&vT[(((size_t)(b*16+hh))*32 + dh)*512 + ll] = pv;
      } else {
        #pragma unroll
        for (int i = 0; i < 4; ++i){
          int row = row0 + i;
          float v = acc[fm][fn][i] + bb;
          if (epi == 1){
            v = res[(size_t)row*N + n] + te[(row>>9)*D_ + n]
              + (float)gate[(size_t)row*gate_ld + n]*v;
            outf[(size_t)row*N + n] = v;
          } else if (epi == 2){
            outb[(size_t)row*N + n] = (bf16_t)geluf(v);
          } else if (epi == 3){
            outb[(size_t)row*N + n] = (bf16_t)v;
          } else if (epi == 4){
            v = res[(size_t)row*N + n] + (float)gate[(size_t)row*gate_ld + n]*v;
            outf[(size_t)row*N + n] = v;
          } else {
            outb[(size_t)row*N + n] = (bf16_t)v;
          }
        }
      }
    }
  }
}

// ---------------- MFMA attention: block = (b,h,16-row q-tile) ----------------
__global__ __launch_bounds__(256) void k_attn2(const bf16_t* __restrict__ qkv,
      const bf16_t* __restrict__ vT, const bf16_t* __restrict__ pfb,
      const float* __restrict__ keepf, bf16_t* __restrict__ obuf){
  __shared__ float ss[16][516];
  __shared__ float opart[4][16][33];
  __shared__ float inv_s[16];
  int blk = blockIdx.x;
  int qt = blk & 31;
  int bh = blk >> 5;
  int b = bh >> 4, h = bh & 15;
  int r0 = qt*16;
  int tid = threadIdx.x;
  int lane = tid & 63, w = tid >> 6;
  int frow = lane & 15, g = lane >> 4;
  const float scale = 0.17677669529663687f;  // 1/sqrt(32)
  bf16x8 qf = *(const bf16x8*)(qkv + (size_t)(b*512 + r0 + frow)*1536 + h*32 + g*8);
  // phase 1: S = QK^T*scale + pfb, masked; wave w covers k in [w*128, w*128+128)
  #pragma unroll
  for (int t = 0; t < 8; ++t){
    int kc = w*128 + t*16;
    bf16x8 kf = *(const bf16x8*)(qkv + (size_t)(b*512 + kc + frow)*1536 + 512 + h*32 + g*8);
    f32x4 s4 = {};
    s4 = __builtin_amdgcn_mfma_f32_16x16x32_bf16(qf, kf, s4, 0,0,0);
    int tok = kc + frow;
    float kp = keepf[b*512 + tok];
    const bf16_t* pf = pfb + ((size_t)bh*512 + r0 + g*4)*512 + tok;
    #pragma unroll
    for (int i = 0; i < 4; ++i){
      float sv = s4[i]*scale + (float)pf[(size_t)i*512];
      sv = (kp == 0.f) ? -1e9f : sv;
      ss[g*4+i][tok] = sv;
    }
  }
  __syncthreads();
  // softmax (unnormalized e kept in ss; inv_s per row)
  {
    int r = tid >> 4, mo = tid & 15;
    float mx = -INFINITY;
    #pragma unroll 8
    for (int t2 = 0; t2 < 32; ++t2) mx = fmaxf(mx, ss[r][mo + 16*t2]);
    #pragma unroll
    for (int o = 1; o < 16; o <<= 1) mx = fmaxf(mx, __shfl_xor(mx, o));
    float sum = 0.f;
    #pragma unroll 8
    for (int t2 = 0; t2 < 32; ++t2){
      int m = mo + 16*t2;
      float e = __expf(ss[r][m] - mx);
      ss[r][m] = e;
      sum += e;
    }
    #pragma unroll
    for (int o = 1; o < 16; o <<= 1) sum += __shfl_xor(sum, o);
    if (mo == 0) inv_s[r] = 1.f/sum;
  }
  __syncthreads();
  // phase 2: O_partial = P[16, w-range] @ V[w-range, 32]
  f32x4 oacc[2] = {};
  #pragma unroll
  for (int t = 0; t < 4; ++t){
    int kc = w*128 + t*32;
    float4 p0 = *(const float4*)&ss[frow][kc + g*8];
    float4 p1 = *(const float4*)&ss[frow][kc + g*8 + 4];
    bf16x8 pfr;
    pfr[0]=(bf16_t)p0.x; pfr[1]=(bf16_t)p0.y; pfr[2]=(bf16_t)p0.z; pfr[3]=(bf16_t)p0.w;
    pfr[4]=(bf16_t)p1.x; pfr[5]=(bf16_t)p1.y; pfr[6]=(bf16_t)p1.z; pfr[7]=(bf16_t)p1.w;
    #pragma unroll
    for (int fn = 0; fn < 2; ++fn){
      bf16x8 vf = *(const bf16x8*)(vT + ((size_t)bh*32 + fn*16 + frow)*512 + kc + g*8);
      oacc[fn] = __builtin_amdgcn_mfma_f32_16x16x32_bf16(pfr, vf, oacc[fn], 0,0,0);
    }
  }
  #pragma unroll
  for (int fn = 0; fn < 2; ++fn)
    #pragma unroll
    for (int i = 0; i < 4; ++i)
      opart[w][g*4+i][fn*16+frow] = oacc[fn][i];
  __syncthreads();
  // reduce over waves + normalize + write bf16
  {
    int q = tid >> 4, dh = (tid & 15)*2;
    float o0 = 0.f, o1 = 0.f;
    #pragma unroll
    for (int ww = 0; ww < 4; ++ww){ o0 += opart[ww][q][dh]; o1 += opart[ww][q][dh+1]; }
    float inv = inv_s[q];
    bf16x2 ov; ov[0] = (bf16_t)(o0*inv); ov[1] = (bf16_t)(o1*inv);
    *(bf16x2*)(obuf + (size_t)(b*512 + r0 + q)*512 + h*32 + dh) = ov;
  }
}

extern "C" void kernel_launch(void* const* d_in, const int* in_sizes, int n_in,
                              void* d_out, int out_size, void* d_ws, size_t ws_size,
                              hipStream_t stream){
  (void)in_sizes; (void)n_in; (void)out_size; (void)ws_size;
  const float* x        = (const float*)d_in[0];
  const float* pos      = (const float*)d_in[1];
  const float* time_emb = (const float*)d_in[2];
  const float* pair     = (const float*)d_in[3];
  const float* pos_w    = (const float*)d_in[4];
  const float* pfb_w    = (const float*)d_in[5];
  const float* p2n_w1   = (const float*)d_in[6];
  const float* p2n_w2   = (const float*)d_in[7];
  const float* adaln_w  = (const float*)d_in[8];
  const float* adaln_b  = (const float*)d_in[9];
  const float* qkv_w    = (const float*)d_in[10];
  const float* qkv_b    = (const float*)d_in[11];
  const float* proj_w   = (const float*)d_in[12];
  const float* proj_b   = (const float*)d_in[13];
  const float* mlp_w1   = (const float*)d_in[14];
  const float* mlp_b1   = (const float*)d_in[15];
  const float* mlp_w2   = (const float*)d_in[16];
  const float* mlp_b2   = (const float*)d_in[17];
  const int*   maskp    = (const int*)d_in[18];

  float* W = (float*)d_ws;
  size_t off = 0;
  auto alloc = [&](size_t nfw){ float* p = W + off; off += nfw; return p; };
  float*  h     = alloc(524288);
  float*  hin2  = alloc(524288);
  bf16_t* modb  = (bf16_t*)alloc(3145728);   // [1024][6144] bf16, both layers
  float*  colm  = alloc(524288);
  float*  keepf = alloc(1024);
  bf16_t* pfbb  = (bf16_t*)alloc(4194304);   // 8,388,608 bf16
  bf16_t* condb = (bf16_t*)alloc(262144);    // 524,288 bf16
  bf16_t* abuf  = (bf16_t*)alloc(262144);    // 524,288 bf16
  bf16_t* qkvb  = (bf16_t*)alloc(786432);    // 1,572,864 bf16
  bf16_t* vTb   = (bf16_t*)alloc(262144);    // 524,288 bf16
  bf16_t* midb  = (bf16_t*)alloc(1048576);   // 2,097,152 bf16
  bf16_t* obuf  = (bf16_t*)alloc(262144);    // 524,288 bf16
  bf16_t* wB    = (bf16_t*)alloc(4718592);   // 9,437,184 bf16
  bf16_t* wA  = wB;                 // [2][3072][512]
  bf16_t* wQ  = wB + 3145728;
  bf16_t* wP  = wB + 4718592;
  bf16_t* wM1 = wB + 5242880;
  bf16_t* wM2 = wB + 7340032;

  // merged preamble: weight-cvt | posemb | pair-bias+colmean
  k_pre<<<NB_CVT + NB_POS + NT_*2, 256, 0, stream>>>(
      adaln_w, qkv_w, proj_w, mlp_w1, mlp_w2, wB,
      pos, pos_w, maskp, h, keepf,
      pair, pfb_w, pfbb, colm);
  k_topk_f2n<<<NT_, 128, 0, stream>>>(colm, pair, keepf, p2n_w1, p2n_w2, x, condb);
  // batched adaLN for BOTH layers: modb[1024][6144](bf16) = cond @ [2·3072,512]^T + b  (128x128 tiles)
  k_gemm_bf<128,128><<<dim3(48,8), 256, 0, stream>>>(condb, wA, adaln_b,
      NT_, 6144, 512, 0, nullptr, modb, nullptr, nullptr, 0, nullptr, nullptr);

  for (int l = 0; l < NL_; ++l){
    const bf16_t* modl = modb + (size_t)l*3072;
    // a = LN(h+te)*(1+sc_a)+sh_a -> bf16
    k_lnmod2<<<NT_, 128, 0, stream>>>(h, time_emb, modl, abuf, 0, 512, 6144);
    // qkv -> bf16 (+ vT)   64x64 tiles (r5 config)
    k_gemm_bf<64,64><<<dim3(24,16), 256, 0, stream>>>(abuf, wQ + (size_t)l*1536*512,
        qkv_b + (size_t)l*1536, NT_, 1536, 512, 3, nullptr, qkvb, nullptr, nullptr, 0, nullptr, vTb);
    k_attn2<<<B_*H_*32, 256, 0, stream>>>(qkvb, vTb, pfbb, keepf, obuf);
    // hin2 = (h+te) + g_a * (o@proj^T + b)   64x32 tiles
    k_gemm_bf<64,32><<<dim3(16,16), 256, 0, stream>>>(obuf, wP + (size_t)l*512*512,
        proj_b + (size_t)l*512, NT_, 512, 512, 1, hin2, nullptr, h,
        modl + 2*512, 6144, time_emb, nullptr);
    k_lnmod2<<<NT_, 128, 0, stream>>>(hin2, nullptr, modl, abuf, 3*512, 4*512, 6144);
    // mlp1 gelu -> bf16   64x64 tiles (r5 config)
    k_gemm_bf<64,64><<<dim3(32,16), 256, 0, stream>>>(abuf, wM1 + (size_t)l*2048*512,
        mlp_b1 + (size_t)l*2048, NT_, 2048, 512, 2, nullptr, midb, nullptr, nullptr, 0, nullptr, nullptr);
    // h_out = hin2 + g_m * (mid@mlp2^T + b)   64x32 tiles
    float* hout = (l == NL_-1) ? (float*)d_out : h;
    k_gemm_bf<64,32><<<dim3(16,16), 256, 0, stream>>>(midb, wM2 + (size_t)l*512*2048,
        mlp_b2 + (size_t)l*512, NT_, 512, 2048, 4, hout, nullptr, hin2,
        modl + 5*512, 6144, nullptr, nullptr);
  }
}

// Round 8
// 336.629 us; speedup vs baseline: 1.1182x; 1.0491x over previous
//
#include <hip/hip_runtime.h>
#include <hip/hip_bf16.h>
#include <math.h>

#define B_  2
#define L_  512
#define D_  512
#define H_  16
#define P_  128
#define NL_ 2
#define DH_ 32
#define FF_ 2048
#define NT_ (B_*L_)

typedef __bf16 bf16_t;
typedef bf16_t bf16x8 __attribute__((ext_vector_type(8)));
typedef bf16_t bf16x4 __attribute__((ext_vector_type(4)));
typedef bf16_t bf16x2 __attribute__((ext_vector_type(2)));
typedef float  f32x4  __attribute__((ext_vector_type(4)));

__device__ __forceinline__ float siluf(float x){ return x / (1.f + __expf(-x)); }
__device__ __forceinline__ float geluf(float x){
  const float c = 0.7978845608028654f;  // sqrt(2/pi)
  float x3 = x*x*x;
  return 0.5f*x*(1.f + tanhf(c*(x + 0.044715f*x3)));
}

__device__ __forceinline__ void gload16(const bf16_t* g, bf16_t* l){
  __builtin_amdgcn_global_load_lds(
      (const __attribute__((address_space(1))) unsigned int*)g,
      (__attribute__((address_space(3))) unsigned int*)l, 16, 0, 0);
}

// ---------------- merged preamble: cvtw (9216 blocks) | posemb (1024) | pfb2 (2048) ----------------
#define NB_CVT 9216
#define NB_POS 1024
__global__ __launch_bounds__(256) void k_pre(
      const float* __restrict__ s0, const float* __restrict__ s1,
      const float* __restrict__ s2, const float* __restrict__ s3,
      const float* __restrict__ s4, bf16_t* __restrict__ wdst,
      const float* __restrict__ pos, const float* __restrict__ posw,
      const int* __restrict__ maskp, float* __restrict__ h, float* __restrict__ keepf,
      const float* __restrict__ pair, const float* __restrict__ pfw,
      bf16_t* __restrict__ pfb, float* __restrict__ colm){
  __shared__ float sw[16][128];
  int bid = blockIdx.x;
  int tid = threadIdx.x;
  if (bid < NB_CVT){
    const size_t c0=3145728, c1=4718592, c2=5242880, c3=7340032, c4=9437184;
    size_t e = ((size_t)bid*256 + tid)*4;
    if (e >= c4) return;
    const float* s; size_t off;
    if      (e < c0){ s=s0; off=e; }
    else if (e < c1){ s=s1; off=e-c0; }
    else if (e < c2){ s=s2; off=e-c1; }
    else if (e < c3){ s=s3; off=e-c2; }
    else            { s=s4; off=e-c3; }
    float4 v = *(const float4*)(s + off);
    bf16x4 o; o[0]=(bf16_t)v.x; o[1]=(bf16_t)v.y; o[2]=(bf16_t)v.z; o[3]=(bf16_t)v.w;
    *(bf16x4*)(wdst + e) = o;
    return;
  }
  if (bid < NB_CVT + NB_POS){
    int n = bid - NB_CVT;                     // b*L + l
    float kf = (maskp[n] != 0) ? 0.f : 1.f;   // True = pad
    if (tid == 0) keepf[n] = kf;
    float p0 = pos[n*3+0], p1 = pos[n*3+1], p2 = pos[n*3+2];
    for (int d = tid; d < D_; d += 256){
      float v = p0*posw[d*3+0] + p1*posw[d*3+1] + p2*posw[d*3+2];
      h[(size_t)n*D_ + d] = kf*v;
    }
    return;
  }
  // pair bias fused with col-mean
  int blk = bid - NB_CVT - NB_POS;
  int mc = blk & 1;            // m half (256 each)
  int n  = blk >> 1;           // b*L + l
  int b = n >> 9, l = n & 511;
  {
    float4* swv = (float4*)&sw[0][0];
    const float4* wv = (const float4*)pfw;
    swv[tid] = wv[tid];
    swv[tid + 256] = wv[tid + 256];
  }
  __syncthreads();
  int m = mc*256 + tid;
  const float* rowp = pair + (((size_t)n)*512 + m)*128;
  float acc[16] = {};
  #pragma unroll 4
  for (int pc = 0; pc < 32; ++pc){
    float4 v = ((const float4*)rowp)[pc];
    v.x = siluf(v.x); v.y = siluf(v.y); v.z = siluf(v.z); v.w = siluf(v.w);
    #pragma unroll
    for (int hh = 0; hh < 16; ++hh){
      float4 wv = *(const float4*)&sw[hh][pc*4];   // wave-uniform broadcast
      acc[hh] += v.x*wv.x + v.y*wv.y + v.z*wv.z + v.w*wv.w;
    }
  }
  float mean = 0.f;
  #pragma unroll
  for (int hh = 0; hh < 16; ++hh) mean += acc[hh];
  colm[((size_t)n)*512 + m] = mean * (1.f/16.f);
  #pragma unroll
  for (int hh = 0; hh < 16; ++hh)
    pfb[(((size_t)(b*16 + hh))*512 + l)*512 + m] = (bf16_t)acc[hh];
}

// ---------------- top-3 rows per column + pair2node MLP + cond = silu(x + f2n) ----------------
__global__ __launch_bounds__(128) void k_topk_f2n(const float* __restrict__ colm,
      const float* __restrict__ pair, const float* __restrict__ keepf,
      const float* __restrict__ w1, const float* __restrict__ w2,
      const float* __restrict__ xin, bf16_t* __restrict__ cond){
  int n = blockIdx.x; int b = n >> 9, m = n & 511;
  __shared__ int sidx[3];
  __shared__ float f2n_s[128];
  __shared__ float u_s[128];
  int tid = threadIdx.x;
  if (tid < 64){
    const float* colbase = colm + ((size_t)b*512)*512 + m;   // stride 512 over l
    float v[8];
    #pragma unroll
    for (int i = 0; i < 8; ++i) v[i] = colbase[(size_t)(tid + 64*i)*512];
    int c0 = -1, c1 = -1;
    for (int r = 0; r < 3; ++r){
      float bv = -INFINITY; int bi = 1 << 30;
      #pragma unroll
      for (int i = 0; i < 8; ++i){
        int idx = tid + 64*i;
        bool excl = (idx == c0) || (idx == c1);
        float val = v[i];
        if (!excl && (val > bv || (val == bv && idx < bi))){ bv = val; bi = idx; }
      }
      for (int o = 32; o > 0; o >>= 1){
        float ov = __shfl_down(bv, o);
        int   oi = __shfl_down(bi, o);
        if (ov > bv || (ov == bv && oi < bi)){ bv = ov; bi = oi; }
      }
      bi = __shfl(bi, 0);
      if (tid == 0) sidx[r] = bi;
      if (r == 0) c0 = bi; else c1 = bi;
    }
  }
  __syncthreads();
  int i0 = sidx[0], i1 = sidx[1], i2 = sidx[2];
  float kc = keepf[n];
  float k0 = keepf[b*512 + i0], k1 = keepf[b*512 + i1], k2 = keepf[b*512 + i2];
  {
    int p = tid;
    float s = k0*pair[(((size_t)(b*512 + i0))*512 + m)*128 + p]
            + k1*pair[(((size_t)(b*512 + i1))*512 + m)*128 + p]
            + k2*pair[(((size_t)(b*512 + i2))*512 + m)*128 + p];
    f2n_s[p] = s * kc * (1.f/3.f);
  }
  __syncthreads();
  {
    int j = tid;
    const float* wr = w1 + (size_t)j*128;
    float acc = 0.f;
    #pragma unroll 8
    for (int p = 0; p < 128; ++p) acc += f2n_s[p]*wr[p];
    u_s[j] = siluf(acc);
  }
  __syncthreads();
  for (int d = tid; d < 512; d += 128){
    const float* wr = w2 + (size_t)d*128;
    float acc = 0.f;
    #pragma unroll 8
    for (int p = 0; p < 128; ++p) acc += u_s[p]*wr[p];
    float xv = xin[((size_t)(m*2 + b))*512 + d];     // x is [L,B,D]
    cond[(size_t)n*512 + d] = (bf16_t)siluf(xv + acc);
  }
}

// ---------------- LayerNorm(h [+ te]) * (1+sc) + sh -> bf16  (mod in bf16) ----------------
__global__ __launch_bounds__(128) void k_lnmod2(const float* __restrict__ hbase,
      const float* __restrict__ te, const bf16_t* __restrict__ mod,
      bf16_t* __restrict__ out, int sh_off, int sc_off, int mstride){
  int n = blockIdx.x; int b = n >> 9;
  int tid = threadIdx.x;
  float4 v = ((const float4*)(hbase + (size_t)n*512))[tid];
  if (te){
    float4 t = ((const float4*)(te + (size_t)b*512))[tid];
    v.x += t.x; v.y += t.y; v.z += t.z; v.w += t.w;
  }
  float s = v.x + v.y + v.z + v.w;
  float q = v.x*v.x + v.y*v.y + v.z*v.z + v.w*v.w;
  #pragma unroll
  for (int o = 1; o < 64; o <<= 1){ s += __shfl_xor(s, o); q += __shfl_xor(q, o); }
  __shared__ float s2[2], q2[2];
  if ((tid & 63) == 0){ s2[tid >> 6] = s; q2[tid >> 6] = q; }
  __syncthreads();
  float S = s2[0] + s2[1], Q = q2[0] + q2[1];
  float mean = S * (1.f/512.f);
  float var  = Q * (1.f/512.f) - mean*mean;
  float rstd = rsqrtf(var + 1e-5f);
  const bf16_t* mrow = mod + (size_t)n*mstride;
  bf16x4 sc = *(const bf16x4*)(mrow + sc_off + tid*4);
  bf16x4 sh = *(const bf16x4*)(mrow + sh_off + tid*4);
  bf16x4 rv;
  rv[0] = (bf16_t)((v.x - mean)*rstd*(1.f + (float)sc[0]) + (float)sh[0]);
  rv[1] = (bf16_t)((v.y - mean)*rstd*(1.f + (float)sc[1]) + (float)sh[1]);
  rv[2] = (bf16_t)((v.z - mean)*rstd*(1.f + (float)sc[2]) + (float)sh[2]);
  rv[3] = (bf16_t)((v.w - mean)*rstd*(1.f + (float)sc[3]) + (float)sh[3]);
  *(bf16x4*)(out + (size_t)n*512 + tid*4) = rv;
}

// ---------------- bf16 MFMA GEMM, double-buffered global_load_lds staging ----------------
// C[M,N] = epi(A[M,K] @ Bw[N,K]^T + bias)
// epi: 0 plain -> bf16 | 1 proj: outf = res + te + gate*v | 2 gelu->bf16
//      3 qkv->bf16 (+vT for V cols) | 4 mlp2: outf = res + gate*v
template<int BM, int BN>
__global__ __launch_bounds__(256) void k_gemm_bf(const bf16_t* __restrict__ A,
      const bf16_t* __restrict__ Bw, const float* __restrict__ bias,
      int M, int N, int K, int epi,
      float* __restrict__ outf, bf16_t* __restrict__ outb,
      const float* __restrict__ res, const bf16_t* __restrict__ gate, int gate_ld,
      const float* __restrict__ te, bf16_t* __restrict__ vT){
  const int FM = BM/32, FN = BN/32;
  const int CA = BM/32, CB = BN/32;      // 16B staging chunks per thread
  __shared__ __align__(16) bf16_t As[2][BM*64];
  __shared__ __align__(16) bf16_t Bs[2][BN*64];
  int tid = threadIdx.x;
  int m0 = blockIdx.y*BM, n0 = blockIdx.x*BN;
  int lane = tid & 63, wid = tid >> 6;
  int wr = wid >> 1, wc = wid & 1;
  int frow = lane & 15, g = lane >> 4;
  f32x4 acc[FM][FN] = {};

  auto stage = [&](int buf, int k0){
    int e = tid;
    #pragma unroll
    for (int i = 0; i < CA; ++i, e += 256){
      int row = e >> 3, cb = e & 7;
      gload16(A + (size_t)(m0+row)*K + k0 + ((cb ^ (row&7))<<3), &As[buf][e*8]);
    }
    e = tid;
    #pragma unroll
    for (int i = 0; i < CB; ++i, e += 256){
      int row = e >> 3, cb = e & 7;
      gload16(Bw + (size_t)(n0+row)*K + k0 + ((cb ^ (row&7))<<3), &Bs[buf][e*8]);
    }
  };
  auto compute = [&](int buf){
    #pragma unroll
    for (int ks = 0; ks < 2; ++ks){
      bf16x8 af[FM], bfv[FN];
      #pragma unroll
      for (int fm = 0; fm < FM; ++fm){
        int ar = wr*(BM/2) + fm*16 + frow;
        af[fm] = *(const bf16x8*)&As[buf][ar*64 + (((ks*4+g) ^ (ar&7))<<3)];
      }
      #pragma unroll
      for (int fn = 0; fn < FN; ++fn){
        int br = wc*(BN/2) + fn*16 + frow;
        bfv[fn] = *(const bf16x8*)&Bs[buf][br*64 + (((ks*4+g) ^ (br&7))<<3)];
      }
      #pragma unroll
      for (int fm = 0; fm < FM; ++fm)
        #pragma unroll
        for (int fn = 0; fn < FN; ++fn)
          acc[fm][fn] = __builtin_amdgcn_mfma_f32_16x16x32_bf16(af[fm], bfv[fn], acc[fm][fn], 0,0,0);
    }
  };

  stage(0, 0);
  __syncthreads();
  int cur = 0;
  for (int k0 = 64; k0 < K; k0 += 64){
    stage(cur^1, k0);          // prefetch next tile (loads fly during MFMA)
    compute(cur);
    __syncthreads();           // drains prefetch + protects LDS reuse
    cur ^= 1;
  }
  compute(cur);

  #pragma unroll
  for (int fm = 0; fm < FM; ++fm){
    #pragma unroll
    for (int fn = 0; fn < FN; ++fn){
      int n = n0 + wc*(BN/2) + fn*16 + frow;
      float bb = bias[n];
      int row0 = m0 + wr*(BM/2) + fm*16 + g*4;
      if (epi == 3 && n >= 1024){
        int hh = (n-1024)>>5, dh = (n-1024)&31;
        int b = row0>>9, ll = row0&511;
        bf16x4 pv;
        #pragma unroll
        for (int i = 0; i < 4; ++i){
          float v = acc[fm][fn][i] + bb;
          outb[(size_t)(row0+i)*N + n] = (bf16_t)v;
          pv[i] = (bf16_t)v;
        }
        *(bf16x4*)&vT[(((size_t)(b*16+hh))*32 + dh)*512 + ll] = pv;
      } else {
        #pragma unroll
        for (int i = 0; i < 4; ++i){
          int row = row0 + i;
          float v = acc[fm][fn][i] + bb;
          if (epi == 1){
            v = res[(size_t)row*N + n] + te[(row>>9)*D_ + n]
              + (float)gate[(size_t)row*gate_ld + n]*v;
            outf[(size_t)row*N + n] = v;
          } else if (epi == 2){
            outb[(size_t)row*N + n] = (bf16_t)geluf(v);
          } else if (epi == 3){
            outb[(size_t)row*N + n] = (bf16_t)v;
          } else if (epi == 4){
            v = res[(size_t)row*N + n] + (float)gate[(size_t)row*gate_ld + n]*v;
            outf[(size_t)row*N + n] = v;
          } else {
            outb[(size_t)row*N + n] = (bf16_t)v;
          }
        }
      }
    }
  }
}

// ---------------- MFMA attention: block = (b,h,16-row q-tile) ----------------
// phase 1 uses swapped operands mfma(K, Q): lane holds S[q=frow][tok=kc+g*4..+3]
// -> pfb/keepf loads and ss writes are 4-wide vectors.
__global__ __launch_bounds__(256) void k_attn2(const bf16_t* __restrict__ qkv,
      const bf16_t* __restrict__ vT, const bf16_t* __restrict__ pfb,
      const float* __restrict__ keepf, bf16_t* __restrict__ obuf){
  __shared__ float ss[16][516];
  __shared__ float opart[4][16][33];
  __shared__ float inv_s[16];
  int blk = blockIdx.x;
  int qt = blk & 31;
  int bh = blk >> 5;
  int b = bh >> 4, h = bh & 15;
  int r0 = qt*16;
  int tid = threadIdx.x;
  int lane = tid & 63, w = tid >> 6;
  int frow = lane & 15, g = lane >> 4;
  const float scale = 0.17677669529663687f;  // 1/sqrt(32)
  bf16x8 qf = *(const bf16x8*)(qkv + (size_t)(b*512 + r0 + frow)*1536 + h*32 + g*8);
  // phase 1: S^T tile via mfma(K,Q); wave w covers k in [w*128, w*128+128)
  for (int t = 0; t < 8; ++t){
    int kc = w*128 + t*16;
    bf16x8 kf = *(const bf16x8*)(qkv + (size_t)(b*512 + kc + frow)*1536 + 512 + h*32 + g*8);
    f32x4 s4 = {};
    s4 = __builtin_amdgcn_mfma_f32_16x16x32_bf16(kf, qf, s4, 0,0,0);
    int tok0 = kc + g*4;
    float4 kp = *(const float4*)&keepf[b*512 + tok0];
    bf16x4 pb = *(const bf16x4*)&pfb[((size_t)bh*512 + r0 + frow)*512 + tok0];
    float4 sv;
    sv.x = (kp.x == 0.f) ? -1e9f : s4[0]*scale + (float)pb[0];
    sv.y = (kp.y == 0.f) ? -1e9f : s4[1]*scale + (float)pb[1];
    sv.z = (kp.z == 0.f) ? -1e9f : s4[2]*scale + (float)pb[2];
    sv.w = (kp.w == 0.f) ? -1e9f : s4[3]*scale + (float)pb[3];
    *(float4*)&ss[frow][tok0] = sv;
  }
  __syncthreads();
  // softmax (unnormalized e kept in ss; inv_s per row)
  {
    int r = tid >> 4, mo = tid & 15;
    float mx = -INFINITY;
    #pragma unroll 8
    for (int t2 = 0; t2 < 32; ++t2) mx = fmaxf(mx, ss[r][mo + 16*t2]);
    #pragma unroll
    for (int o = 1; o < 16; o <<= 1) mx = fmaxf(mx, __shfl_xor(mx, o));
    float sum = 0.f;
    #pragma unroll 8
    for (int t2 = 0; t2 < 32; ++t2){
      int m = mo + 16*t2;
      float e = __expf(ss[r][m] - mx);
      ss[r][m] = e;
      sum += e;
    }
    #pragma unroll
    for (int o = 1; o < 16; o <<= 1) sum += __shfl_xor(sum, o);
    if (mo == 0) inv_s[r] = 1.f/sum;
  }
  __syncthreads();
  // phase 2: O_partial = P[16, w-range] @ V[w-range, 32]
  f32x4 oacc[2] = {};
  for (int t = 0; t < 4; ++t){
    int kc = w*128 + t*32;
    float4 p0 = *(const float4*)&ss[frow][kc + g*8];
    float4 p1 = *(const float4*)&ss[frow][kc + g*8 + 4];
    bf16x8 pfr;
    pfr[0]=(bf16_t)p0.x; pfr[1]=(bf16_t)p0.y; pfr[2]=(bf16_t)p0.z; pfr[3]=(bf16_t)p0.w;
    pfr[4]=(bf16_t)p1.x; pfr[5]=(bf16_t)p1.y; pfr[6]=(bf16_t)p1.z; pfr[7]=(bf16_t)p1.w;
    #pragma unroll
    for (int fn = 0; fn < 2; ++fn){
      bf16x8 vf = *(const bf16x8*)(vT + ((size_t)bh*32 + fn*16 + frow)*512 + kc + g*8);
      oacc[fn] = __builtin_amdgcn_mfma_f32_16x16x32_bf16(pfr, vf, oacc[fn], 0,0,0);
    }
  }
  #pragma unroll
  for (int fn = 0; fn < 2; ++fn)
    #pragma unroll
    for (int i = 0; i < 4; ++i)
      opart[w][g*4+i][fn*16+frow] = oacc[fn][i];
  __syncthreads();
  // reduce over waves + normalize + write bf16
  {
    int q = tid >> 4, dh = (tid & 15)*2;
    float o0 = 0.f, o1 = 0.f;
    #pragma unroll
    for (int ww = 0; ww < 4; ++ww){ o0 += opart[ww][q][dh]; o1 += opart[ww][q][dh+1]; }
    float inv = inv_s[q];
    bf16x2 ov; ov[0] = (bf16_t)(o0*inv); ov[1] = (bf16_t)(o1*inv);
    *(bf16x2*)(obuf + (size_t)(b*512 + r0 + q)*512 + h*32 + dh) = ov;
  }
}

extern "C" void kernel_launch(void* const* d_in, const int* in_sizes, int n_in,
                              void* d_out, int out_size, void* d_ws, size_t ws_size,
                              hipStream_t stream){
  (void)in_sizes; (void)n_in; (void)out_size; (void)ws_size;
  const float* x        = (const float*)d_in[0];
  const float* pos      = (const float*)d_in[1];
  const float* time_emb = (const float*)d_in[2];
  const float* pair     = (const float*)d_in[3];
  const float* pos_w    = (const float*)d_in[4];
  const float* pfb_w    = (const float*)d_in[5];
  const float* p2n_w1   = (const float*)d_in[6];
  const float* p2n_w2   = (const float*)d_in[7];
  const float* adaln_w  = (const float*)d_in[8];
  const float* adaln_b  = (const float*)d_in[9];
  const float* qkv_w    = (const float*)d_in[10];
  const float* qkv_b    = (const float*)d_in[11];
  const float* proj_w   = (const float*)d_in[12];
  const float* proj_b   = (const float*)d_in[13];
  const float* mlp_w1   = (const float*)d_in[14];
  const float* mlp_b1   = (const float*)d_in[15];
  const float* mlp_w2   = (const float*)d_in[16];
  const float* mlp_b2   = (const float*)d_in[17];
  const int*   maskp    = (const int*)d_in[18];

  float* W = (float*)d_ws;
  size_t off = 0;
  auto alloc = [&](size_t nfw){ float* p = W + off; off += nfw; return p; };
  float*  h     = alloc(524288);
  float*  hin2  = alloc(524288);
  bf16_t* modb  = (bf16_t*)alloc(3145728);   // [1024][6144] bf16, both layers
  float*  colm  = alloc(524288);
  float*  keepf = alloc(1024);
  bf16_t* pfbb  = (bf16_t*)alloc(4194304);   // 8,388,608 bf16
  bf16_t* condb = (bf16_t*)alloc(262144);    // 524,288 bf16
  bf16_t* abuf  = (bf16_t*)alloc(262144);    // 524,288 bf16
  bf16_t* qkvb  = (bf16_t*)alloc(786432);    // 1,572,864 bf16
  bf16_t* vTb   = (bf16_t*)alloc(262144);    // 524,288 bf16
  bf16_t* midb  = (bf16_t*)alloc(1048576);   // 2,097,152 bf16
  bf16_t* obuf  = (bf16_t*)alloc(262144);    // 524,288 bf16
  bf16_t* wB    = (bf16_t*)alloc(4718592);   // 9,437,184 bf16
  bf16_t* wA  = wB;                 // [2][3072][512]
  bf16_t* wQ  = wB + 3145728;
  bf16_t* wP  = wB + 4718592;
  bf16_t* wM1 = wB + 5242880;
  bf16_t* wM2 = wB + 7340032;

  // merged preamble: weight-cvt | posemb | pair-bias+colmean
  k_pre<<<NB_CVT + NB_POS + NT_*2, 256, 0, stream>>>(
      adaln_w, qkv_w, proj_w, mlp_w1, mlp_w2, wB,
      pos, pos_w, maskp, h, keepf,
      pair, pfb_w, pfbb, colm);
  k_topk_f2n<<<NT_, 128, 0, stream>>>(colm, pair, keepf, p2n_w1, p2n_w2, x, condb);
  // batched adaLN for BOTH layers: modb[1024][6144](bf16) = cond @ [2·3072,512]^T + b  (64x64, r5 config)
  k_gemm_bf<64,64><<<dim3(96,16), 256, 0, stream>>>(condb, wA, adaln_b,
      NT_, 6144, 512, 0, nullptr, modb, nullptr, nullptr, 0, nullptr, nullptr);

  for (int l = 0; l < NL_; ++l){
    const bf16_t* modl = modb + (size_t)l*3072;
    // a = LN(h+te)*(1+sc_a)+sh_a -> bf16
    k_lnmod2<<<NT_, 128, 0, stream>>>(h, time_emb, modl, abuf, 0, 512, 6144);
    // qkv -> bf16 (+ vT)   64x64 tiles
    k_gemm_bf<64,64><<<dim3(24,16), 256, 0, stream>>>(abuf, wQ + (size_t)l*1536*512,
        qkv_b + (size_t)l*1536, NT_, 1536, 512, 3, nullptr, qkvb, nullptr, nullptr, 0, nullptr, vTb);
    k_attn2<<<B_*H_*32, 256, 0, stream>>>(qkvb, vTb, pfbb, keepf, obuf);
    // hin2 = (h+te) + g_a * (o@proj^T + b)   64x32 tiles
    k_gemm_bf<64,32><<<dim3(16,16), 256, 0, stream>>>(obuf, wP + (size_t)l*512*512,
        proj_b + (size_t)l*512, NT_, 512, 512, 1, hin2, nullptr, h,
        modl + 2*512, 6144, time_emb, nullptr);
    k_lnmod2<<<NT_, 128, 0, stream>>>(hin2, nullptr, modl, abuf, 3*512, 4*512, 6144);
    // mlp1 gelu -> bf16   64x64 tiles
    k_gemm_bf<64,64><<<dim3(32,16), 256, 0, stream>>>(abuf, wM1 + (size_t)l*2048*512,
        mlp_b1 + (size_t)l*2048, NT_, 2048, 512, 2, nullptr, midb, nullptr, nullptr, 0, nullptr, nullptr);
    // h_out = hin2 + g_m * (mid@mlp2^T + b)   64x32 tiles
    float* hout = (l == NL_-1) ? (float*)d_out : h;
    k_gemm_bf<64,32><<<dim3(16,16), 256, 0, stream>>>(midb, wM2 + (size_t)l*512*2048,
        mlp_b2 + (size_t)l*512, NT_, 512, 2048, 4, hout, nullptr, hin2,
        modl + 5*512, 6144, nullptr, nullptr);
  }
}

// Round 9
// 336.415 us; speedup vs baseline: 1.1189x; 1.0006x over previous
//
#include <hip/hip_runtime.h>
#include <hip/hip_bf16.h>
#include <math.h>

#define B_  2
#define L_  512
#define D_  512
#define H_  16
#define P_  128
#define NL_ 2
#define DH_ 32
#define FF_ 2048
#define NT_ (B_*L_)

typedef __bf16 bf16_t;
typedef bf16_t bf16x8 __attribute__((ext_vector_type(8)));
typedef bf16_t bf16x4 __attribute__((ext_vector_type(4)));
typedef bf16_t bf16x2 __attribute__((ext_vector_type(2)));
typedef float  f32x4  __attribute__((ext_vector_type(4)));

__device__ __forceinline__ float siluf(float x){ return x / (1.f + __expf(-x)); }
__device__ __forceinline__ float geluf(float x){
  const float c = 0.7978845608028654f;  // sqrt(2/pi)
  float x3 = x*x*x;
  return 0.5f*x*(1.f + tanhf(c*(x + 0.044715f*x3)));
}

__device__ __forceinline__ void gload16(const bf16_t* g, bf16_t* l){
  __builtin_amdgcn_global_load_lds(
      (const __attribute__((address_space(1))) unsigned int*)g,
      (__attribute__((address_space(3))) unsigned int*)l, 16, 0, 0);
}

// ---------------- merged preamble: cvtw (9216 blocks) | posemb (1024) | pfb2 (2048) ----------------
#define NB_CVT 9216
#define NB_POS 1024
__global__ __launch_bounds__(256) void k_pre(
      const float* __restrict__ s0, const float* __restrict__ s1,
      const float* __restrict__ s2, const float* __restrict__ s3,
      const float* __restrict__ s4, bf16_t* __restrict__ wdst,
      const float* __restrict__ pos, const float* __restrict__ posw,
      const int* __restrict__ maskp, float* __restrict__ h, float* __restrict__ keepf,
      const float* __restrict__ pair, const float* __restrict__ pfw,
      bf16_t* __restrict__ pfb, float* __restrict__ colm){
  __shared__ float sw[16][128];
  int bid = blockIdx.x;
  int tid = threadIdx.x;
  if (bid < NB_CVT){
    const size_t c0=3145728, c1=4718592, c2=5242880, c3=7340032, c4=9437184;
    size_t e = ((size_t)bid*256 + tid)*4;
    if (e >= c4) return;
    const float* s; size_t off;
    if      (e < c0){ s=s0; off=e; }
    else if (e < c1){ s=s1; off=e-c0; }
    else if (e < c2){ s=s2; off=e-c1; }
    else if (e < c3){ s=s3; off=e-c2; }
    else            { s=s4; off=e-c3; }
    float4 v = *(const float4*)(s + off);
    bf16x4 o; o[0]=(bf16_t)v.x; o[1]=(bf16_t)v.y; o[2]=(bf16_t)v.z; o[3]=(bf16_t)v.w;
    *(bf16x4*)(wdst + e) = o;
    return;
  }
  if (bid < NB_CVT + NB_POS){
    int n = bid - NB_CVT;                     // b*L + l
    float kf = (maskp[n] != 0) ? 0.f : 1.f;   // True = pad
    if (tid == 0) keepf[n] = kf;
    float p0 = pos[n*3+0], p1 = pos[n*3+1], p2 = pos[n*3+2];
    for (int d = tid; d < D_; d += 256){
      float v = p0*posw[d*3+0] + p1*posw[d*3+1] + p2*posw[d*3+2];
      h[(size_t)n*D_ + d] = kf*v;
    }
    return;
  }
  // pair bias fused with col-mean
  int blk = bid - NB_CVT - NB_POS;
  int mc = blk & 1;            // m half (256 each)
  int n  = blk >> 1;           // b*L + l
  int b = n >> 9, l = n & 511;
  {
    float4* swv = (float4*)&sw[0][0];
    const float4* wv = (const float4*)pfw;
    swv[tid] = wv[tid];
    swv[tid + 256] = wv[tid + 256];
  }
  __syncthreads();
  int m = mc*256 + tid;
  const float* rowp = pair + (((size_t)n)*512 + m)*128;
  float acc[16] = {};
  #pragma unroll 4
  for (int pc = 0; pc < 32; ++pc){
    float4 v = ((const float4*)rowp)[pc];
    v.x = siluf(v.x); v.y = siluf(v.y); v.z = siluf(v.z); v.w = siluf(v.w);
    #pragma unroll
    for (int hh = 0; hh < 16; ++hh){
      float4 wv = *(const float4*)&sw[hh][pc*4];   // wave-uniform broadcast
      acc[hh] += v.x*wv.x + v.y*wv.y + v.z*wv.z + v.w*wv.w;
    }
  }
  float mean = 0.f;
  #pragma unroll
  for (int hh = 0; hh < 16; ++hh) mean += acc[hh];
  colm[((size_t)n)*512 + m] = mean * (1.f/16.f);
  #pragma unroll
  for (int hh = 0; hh < 16; ++hh)
    pfb[(((size_t)(b*16 + hh))*512 + l)*512 + m] = (bf16_t)acc[hh];
}

// ---------------- top-3 rows per column + pair2node MLP + cond = silu(x + f2n) ----------------
__global__ __launch_bounds__(128) void k_topk_f2n(const float* __restrict__ colm,
      const float* __restrict__ pair, const float* __restrict__ keepf,
      const float* __restrict__ w1, const float* __restrict__ w2,
      const float* __restrict__ xin, bf16_t* __restrict__ cond){
  int n = blockIdx.x; int b = n >> 9, m = n & 511;
  __shared__ int sidx[3];
  __shared__ float f2n_s[128];
  __shared__ float u_s[128];
  int tid = threadIdx.x;
  if (tid < 64){
    const float* colbase = colm + ((size_t)b*512)*512 + m;   // stride 512 over l
    float v[8];
    #pragma unroll
    for (int i = 0; i < 8; ++i) v[i] = colbase[(size_t)(tid + 64*i)*512];
    int c0 = -1, c1 = -1;
    for (int r = 0; r < 3; ++r){
      float bv = -INFINITY; int bi = 1 << 30;
      #pragma unroll
      for (int i = 0; i < 8; ++i){
        int idx = tid + 64*i;
        bool excl = (idx == c0) || (idx == c1);
        float val = v[i];
        if (!excl && (val > bv || (val == bv && idx < bi))){ bv = val; bi = idx; }
      }
      for (int o = 32; o > 0; o >>= 1){
        float ov = __shfl_down(bv, o);
        int   oi = __shfl_down(bi, o);
        if (ov > bv || (ov == bv && oi < bi)){ bv = ov; bi = oi; }
      }
      bi = __shfl(bi, 0);
      if (tid == 0) sidx[r] = bi;
      if (r == 0) c0 = bi; else c1 = bi;
    }
  }
  __syncthreads();
  int i0 = sidx[0], i1 = sidx[1], i2 = sidx[2];
  float kc = keepf[n];
  float k0 = keepf[b*512 + i0], k1 = keepf[b*512 + i1], k2 = keepf[b*512 + i2];
  {
    int p = tid;
    float s = k0*pair[(((size_t)(b*512 + i0))*512 + m)*128 + p]
            + k1*pair[(((size_t)(b*512 + i1))*512 + m)*128 + p]
            + k2*pair[(((size_t)(b*512 + i2))*512 + m)*128 + p];
    f2n_s[p] = s * kc * (1.f/3.f);
  }
  __syncthreads();
  {
    int j = tid;
    const float* wr = w1 + (size_t)j*128;
    float acc = 0.f;
    #pragma unroll 8
    for (int p = 0; p < 128; ++p) acc += f2n_s[p]*wr[p];
    u_s[j] = siluf(acc);
  }
  __syncthreads();
  for (int d = tid; d < 512; d += 128){
    const float* wr = w2 + (size_t)d*128;
    float acc = 0.f;
    #pragma unroll 8
    for (int p = 0; p < 128; ++p) acc += u_s[p]*wr[p];
    float xv = xin[((size_t)(m*2 + b))*512 + d];     // x is [L,B,D]
    cond[(size_t)n*512 + d] = (bf16_t)siluf(xv + acc);
  }
}

// ---------------- LayerNorm(h [+ te]) * (1+sc) + sh -> bf16  (mod in bf16) ----------------
__global__ __launch_bounds__(128) void k_lnmod2(const float* __restrict__ hbase,
      const float* __restrict__ te, const bf16_t* __restrict__ mod,
      bf16_t* __restrict__ out, int sh_off, int sc_off, int mstride){
  int n = blockIdx.x; int b = n >> 9;
  int tid = threadIdx.x;
  float4 v = ((const float4*)(hbase + (size_t)n*512))[tid];
  if (te){
    float4 t = ((const float4*)(te + (size_t)b*512))[tid];
    v.x += t.x; v.y += t.y; v.z += t.z; v.w += t.w;
  }
  float s = v.x + v.y + v.z + v.w;
  float q = v.x*v.x + v.y*v.y + v.z*v.z + v.w*v.w;
  #pragma unroll
  for (int o = 1; o < 64; o <<= 1){ s += __shfl_xor(s, o); q += __shfl_xor(q, o); }
  __shared__ float s2[2], q2[2];
  if ((tid & 63) == 0){ s2[tid >> 6] = s; q2[tid >> 6] = q; }
  __syncthreads();
  float S = s2[0] + s2[1], Q = q2[0] + q2[1];
  float mean = S * (1.f/512.f);
  float var  = Q * (1.f/512.f) - mean*mean;
  float rstd = rsqrtf(var + 1e-5f);
  const bf16_t* mrow = mod + (size_t)n*mstride;
  bf16x4 sc = *(const bf16x4*)(mrow + sc_off + tid*4);
  bf16x4 sh = *(const bf16x4*)(mrow + sh_off + tid*4);
  bf16x4 rv;
  rv[0] = (bf16_t)((v.x - mean)*rstd*(1.f + (float)sc[0]) + (float)sh[0]);
  rv[1] = (bf16_t)((v.y - mean)*rstd*(1.f + (float)sc[1]) + (float)sh[1]);
  rv[2] = (bf16_t)((v.z - mean)*rstd*(1.f + (float)sc[2]) + (float)sh[2]);
  rv[3] = (bf16_t)((v.w - mean)*rstd*(1.f + (float)sc[3]) + (float)sh[3]);
  *(bf16x4*)(out + (size_t)n*512 + tid*4) = rv;
}

// ---------------- bf16 MFMA GEMM, double-buffered global_load_lds staging ----------------
// C[M,N] = epi(A[M,K] @ Bw[N,K]^T + bias)
// epi: 0 plain -> bf16 | 1 proj: outf = res + te + gate*v | 2 gelu->bf16
//      3 qkv->bf16 (+vT for V cols) | 4 mlp2: outf = res + gate*v
template<int BM, int BN>
__global__ __launch_bounds__(256) void k_gemm_bf(const bf16_t* __restrict__ A,
      const bf16_t* __restrict__ Bw, const float* __restrict__ bias,
      int M, int N, int K, int epi,
      float* __restrict__ outf, bf16_t* __restrict__ outb,
      const float* __restrict__ res, const bf16_t* __restrict__ gate, int gate_ld,
      const float* __restrict__ te, bf16_t* __restrict__ vT){
  const int FM = BM/32, FN = BN/32;
  const int CA = BM/32, CB = BN/32;      // 16B staging chunks per thread
  __shared__ __align__(16) bf16_t As[2][BM*64];
  __shared__ __align__(16) bf16_t Bs[2][BN*64];
  int tid = threadIdx.x;
  int m0 = blockIdx.y*BM, n0 = blockIdx.x*BN;
  int lane = tid & 63, wid = tid >> 6;
  int wr = wid >> 1, wc = wid & 1;
  int frow = lane & 15, g = lane >> 4;
  f32x4 acc[FM][FN] = {};

  auto stage = [&](int buf, int k0){
    int e = tid;
    #pragma unroll
    for (int i = 0; i < CA; ++i, e += 256){
      int row = e >> 3, cb = e & 7;
      gload16(A + (size_t)(m0+row)*K + k0 + ((cb ^ (row&7))<<3), &As[buf][e*8]);
    }
    e = tid;
    #pragma unroll
    for (int i = 0; i < CB; ++i, e += 256){
      int row = e >> 3, cb = e & 7;
      gload16(Bw + (size_t)(n0+row)*K + k0 + ((cb ^ (row&7))<<3), &Bs[buf][e*8]);
    }
  };
  auto compute = [&](int buf){
    #pragma unroll
    for (int ks = 0; ks < 2; ++ks){
      bf16x8 af[FM], bfv[FN];
      #pragma unroll
      for (int fm = 0; fm < FM; ++fm){
        int ar = wr*(BM/2) + fm*16 + frow;
        af[fm] = *(const bf16x8*)&As[buf][ar*64 + (((ks*4+g) ^ (ar&7))<<3)];
      }
      #pragma unroll
      for (int fn = 0; fn < FN; ++fn){
        int br = wc*(BN/2) + fn*16 + frow;
        bfv[fn] = *(const bf16x8*)&Bs[buf][br*64 + (((ks*4+g) ^ (br&7))<<3)];
      }
      #pragma unroll
      for (int fm = 0; fm < FM; ++fm)
        #pragma unroll
        for (int fn = 0; fn < FN; ++fn)
          acc[fm][fn] = __builtin_amdgcn_mfma_f32_16x16x32_bf16(af[fm], bfv[fn], acc[fm][fn], 0,0,0);
    }
  };

  stage(0, 0);
  __syncthreads();
  int cur = 0;
  for (int k0 = 64; k0 < K; k0 += 64){
    stage(cur^1, k0);          // prefetch next tile (loads fly during MFMA)
    compute(cur);
    __syncthreads();           // drains prefetch + protects LDS reuse
    cur ^= 1;
  }
  compute(cur);

  #pragma unroll
  for (int fm = 0; fm < FM; ++fm){
    #pragma unroll
    for (int fn = 0; fn < FN; ++fn){
      int n = n0 + wc*(BN/2) + fn*16 + frow;
      float bb = bias[n];
      int row0 = m0 + wr*(BM/2) + fm*16 + g*4;
      if (epi == 3 && n >= 1024){
        int hh = (n-1024)>>5, dh = (n-1024)&31;
        int b = row0>>9, ll = row0&511;
        bf16x4 pv;
        #pragma unroll
        for (int i = 0; i < 4; ++i){
          float v = acc[fm][fn][i] + bb;
          outb[(size_t)(row0+i)*N + n] = (bf16_t)v;
          pv[i] = (bf16_t)v;
        }
        *(bf16x4*)&vT[(((size_t)(b*16+hh))*32 + dh)*512 + ll] = pv;
      } else {
        #pragma unroll
        for (int i = 0; i < 4; ++i){
          int row = row0 + i;
          float v = acc[fm][fn][i] + bb;
          if (epi == 1){
            v = res[(size_t)row*N + n] + te[(row>>9)*D_ + n]
              + (float)gate[(size_t)row*gate_ld + n]*v;
            outf[(size_t)row*N + n] = v;
          } else if (epi == 2){
            outb[(size_t)row*N + n] = (bf16_t)geluf(v);
          } else if (epi == 3){
            outb[(size_t)row*N + n] = (bf16_t)v;
          } else if (epi == 4){
            v = res[(size_t)row*N + n] + (float)gate[(size_t)row*gate_ld + n]*v;
            outf[(size_t)row*N + n] = v;
          } else {
            outb[(size_t)row*N + n] = (bf16_t)v;
          }
        }
      }
    }
  }
}

// ---------------- MFMA attention: block = (b,h,16-row q-tile) ----------------
// phase 1: swapped mfma(K,Q) with K fragments prefetched 8-deep (T14 issue-early);
// V fragments prefetched before softmax so their latency hides under it.
__global__ __launch_bounds__(256) void k_attn2(const bf16_t* __restrict__ qkv,
      const bf16_t* __restrict__ vT, const bf16_t* __restrict__ pfb,
      const float* __restrict__ keepf, bf16_t* __restrict__ obuf){
  __shared__ float ss[16][516];
  __shared__ float opart[4][16][33];
  __shared__ float inv_s[16];
  int blk = blockIdx.x;
  int qt = blk & 31;
  int bh = blk >> 5;
  int b = bh >> 4, h = bh & 15;
  int r0 = qt*16;
  int tid = threadIdx.x;
  int lane = tid & 63, w = tid >> 6;
  int frow = lane & 15, g = lane >> 4;
  const float scale = 0.17677669529663687f;  // 1/sqrt(32)
  bf16x8 qf = *(const bf16x8*)(qkv + (size_t)(b*512 + r0 + frow)*1536 + h*32 + g*8);
  // issue all 8 K-fragment loads (independent; 8 in flight)
  bf16x8 kf[8];
  #pragma unroll
  for (int t = 0; t < 8; ++t){
    int kc = w*128 + t*16;
    kf[t] = *(const bf16x8*)(qkv + (size_t)(b*512 + kc + frow)*1536 + 512 + h*32 + g*8);
  }
  // phase 1: S^T tile via mfma(K,Q); lane holds S[q=frow][tok=kc+g*4..+3]
  #pragma unroll
  for (int t = 0; t < 8; ++t){
    int kc = w*128 + t*16;
    f32x4 s4 = {};
    s4 = __builtin_amdgcn_mfma_f32_16x16x32_bf16(kf[t], qf, s4, 0,0,0);
    int tok0 = kc + g*4;
    float4 kp = *(const float4*)&keepf[b*512 + tok0];
    bf16x4 pb = *(const bf16x4*)&pfb[((size_t)bh*512 + r0 + frow)*512 + tok0];
    float4 sv;
    sv.x = (kp.x == 0.f) ? -1e9f : s4[0]*scale + (float)pb[0];
    sv.y = (kp.y == 0.f) ? -1e9f : s4[1]*scale + (float)pb[1];
    sv.z = (kp.z == 0.f) ? -1e9f : s4[2]*scale + (float)pb[2];
    sv.w = (kp.w == 0.f) ? -1e9f : s4[3]*scale + (float)pb[3];
    *(float4*)&ss[frow][tok0] = sv;
  }
  // prefetch all 8 V fragments now; latency hides under the softmax phase
  bf16x8 vf[4][2];
  #pragma unroll
  for (int t = 0; t < 4; ++t){
    int kc = w*128 + t*32;
    #pragma unroll
    for (int fn = 0; fn < 2; ++fn)
      vf[t][fn] = *(const bf16x8*)(vT + ((size_t)bh*32 + fn*16 + frow)*512 + kc + g*8);
  }
  __syncthreads();
  // softmax (unnormalized e kept in ss; inv_s per row)
  {
    int r = tid >> 4, mo = tid & 15;
    float mx = -INFINITY;
    #pragma unroll 8
    for (int t2 = 0; t2 < 32; ++t2) mx = fmaxf(mx, ss[r][mo + 16*t2]);
    #pragma unroll
    for (int o = 1; o < 16; o <<= 1) mx = fmaxf(mx, __shfl_xor(mx, o));
    float sum = 0.f;
    #pragma unroll 8
    for (int t2 = 0; t2 < 32; ++t2){
      int m = mo + 16*t2;
      float e = __expf(ss[r][m] - mx);
      ss[r][m] = e;
      sum += e;
    }
    #pragma unroll
    for (int o = 1; o < 16; o <<= 1) sum += __shfl_xor(sum, o);
    if (mo == 0) inv_s[r] = 1.f/sum;
  }
  __syncthreads();
  // phase 2: O_partial = P[16, w-range] @ V[w-range, 32]  (V already in registers)
  f32x4 oacc[2] = {};
  #pragma unroll
  for (int t = 0; t < 4; ++t){
    int kc = w*128 + t*32;
    float4 p0 = *(const float4*)&ss[frow][kc + g*8];
    float4 p1 = *(const float4*)&ss[frow][kc + g*8 + 4];
    bf16x8 pfr;
    pfr[0]=(bf16_t)p0.x; pfr[1]=(bf16_t)p0.y; pfr[2]=(bf16_t)p0.z; pfr[3]=(bf16_t)p0.w;
    pfr[4]=(bf16_t)p1.x; pfr[5]=(bf16_t)p1.y; pfr[6]=(bf16_t)p1.z; pfr[7]=(bf16_t)p1.w;
    #pragma unroll
    for (int fn = 0; fn < 2; ++fn)
      oacc[fn] = __builtin_amdgcn_mfma_f32_16x16x32_bf16(pfr, vf[t][fn], oacc[fn], 0,0,0);
  }
  #pragma unroll
  for (int fn = 0; fn < 2; ++fn)
    #pragma unroll
    for (int i = 0; i < 4; ++i)
      opart[w][g*4+i][fn*16+frow] = oacc[fn][i];
  __syncthreads();
  // reduce over waves + normalize + write bf16
  {
    int q = tid >> 4, dh = (tid & 15)*2;
    float o0 = 0.f, o1 = 0.f;
    #pragma unroll
    for (int ww = 0; ww < 4; ++ww){ o0 += opart[ww][q][dh]; o1 += opart[ww][q][dh+1]; }
    float inv = inv_s[q];
    bf16x2 ov; ov[0] = (bf16_t)(o0*inv); ov[1] = (bf16_t)(o1*inv);
    *(bf16x2*)(obuf + (size_t)(b*512 + r0 + q)*512 + h*32 + dh) = ov;
  }
}

extern "C" void kernel_launch(void* const* d_in, const int* in_sizes, int n_in,
                              void* d_out, int out_size, void* d_ws, size_t ws_size,
                              hipStream_t stream){
  (void)in_sizes; (void)n_in; (void)out_size; (void)ws_size;
  const float* x        = (const float*)d_in[0];
  const float* pos      = (const float*)d_in[1];
  const float* time_emb = (const float*)d_in[2];
  const float* pair     = (const float*)d_in[3];
  const float* pos_w    = (const float*)d_in[4];
  const float* pfb_w    = (const float*)d_in[5];
  const float* p2n_w1   = (const float*)d_in[6];
  const float* p2n_w2   = (const float*)d_in[7];
  const float* adaln_w  = (const float*)d_in[8];
  const float* adaln_b  = (const float*)d_in[9];
  const float* qkv_w    = (const float*)d_in[10];
  const float* qkv_b    = (const float*)d_in[11];
  const float* proj_w   = (const float*)d_in[12];
  const float* proj_b   = (const float*)d_in[13];
  const float* mlp_w1   = (const float*)d_in[14];
  const float* mlp_b1   = (const float*)d_in[15];
  const float* mlp_w2   = (const float*)d_in[16];
  const float* mlp_b2   = (const float*)d_in[17];
  const int*   maskp    = (const int*)d_in[18];

  float* W = (float*)d_ws;
  size_t off = 0;
  auto alloc = [&](size_t nfw){ float* p = W + off; off += nfw; return p; };
  float*  h     = alloc(524288);
  float*  hin2  = alloc(524288);
  bf16_t* modb  = (bf16_t*)alloc(3145728);   // [1024][6144] bf16, both layers
  float*  colm  = alloc(524288);
  float*  keepf = alloc(1024);
  bf16_t* pfbb  = (bf16_t*)alloc(4194304);   // 8,388,608 bf16
  bf16_t* condb = (bf16_t*)alloc(262144);    // 524,288 bf16
  bf16_t* abuf  = (bf16_t*)alloc(262144);    // 524,288 bf16
  bf16_t* qkvb  = (bf16_t*)alloc(786432);    // 1,572,864 bf16
  bf16_t* vTb   = (bf16_t*)alloc(262144);    // 524,288 bf16
  bf16_t* midb  = (bf16_t*)alloc(1048576);   // 2,097,152 bf16
  bf16_t* obuf  = (bf16_t*)alloc(262144);    // 524,288 bf16
  bf16_t* wB    = (bf16_t*)alloc(4718592);   // 9,437,184 bf16
  bf16_t* wA  = wB;                 // [2][3072][512]
  bf16_t* wQ  = wB + 3145728;
  bf16_t* wP  = wB + 4718592;
  bf16_t* wM1 = wB + 5242880;
  bf16_t* wM2 = wB + 7340032;

  // merged preamble: weight-cvt | posemb | pair-bias+colmean
  k_pre<<<NB_CVT + NB_POS + NT_*2, 256, 0, stream>>>(
      adaln_w, qkv_w, proj_w, mlp_w1, mlp_w2, wB,
      pos, pos_w, maskp, h, keepf,
      pair, pfb_w, pfbb, colm);
  k_topk_f2n<<<NT_, 128, 0, stream>>>(colm, pair, keepf, p2n_w1, p2n_w2, x, condb);
  // batched adaLN for BOTH layers: modb[1024][6144](bf16) = cond @ [2·3072,512]^T + b  (64x64)
  k_gemm_bf<64,64><<<dim3(96,16), 256, 0, stream>>>(condb, wA, adaln_b,
      NT_, 6144, 512, 0, nullptr, modb, nullptr, nullptr, 0, nullptr, nullptr);

  for (int l = 0; l < NL_; ++l){
    const bf16_t* modl = modb + (size_t)l*3072;
    // a = LN(h+te)*(1+sc_a)+sh_a -> bf16
    k_lnmod2<<<NT_, 128, 0, stream>>>(h, time_emb, modl, abuf, 0, 512, 6144);
    // qkv -> bf16 (+ vT)   64x64 tiles
    k_gemm_bf<64,64><<<dim3(24,16), 256, 0, stream>>>(abuf, wQ + (size_t)l*1536*512,
        qkv_b + (size_t)l*1536, NT_, 1536, 512, 3, nullptr, qkvb, nullptr, nullptr, 0, nullptr, vTb);
    k_attn2<<<B_*H_*32, 256, 0, stream>>>(qkvb, vTb, pfbb, keepf, obuf);
    // hin2 = (h+te) + g_a * (o@proj^T + b)   64x32 tiles
    k_gemm_bf<64,32><<<dim3(16,16), 256, 0, stream>>>(obuf, wP + (size_t)l*512*512,
        proj_b + (size_t)l*512, NT_, 512, 512, 1, hin2, nullptr, h,
        modl + 2*512, 6144, time_emb, nullptr);
    k_lnmod2<<<NT_, 128, 0, stream>>>(hin2, nullptr, modl, abuf, 3*512, 4*512, 6144);
    // mlp1 gelu -> bf16   64x64 tiles
    k_gemm_bf<64,64><<<dim3(32,16), 256, 0, stream>>>(abuf, wM1 + (size_t)l*2048*512,
        mlp_b1 + (size_t)l*2048, NT_, 2048, 512, 2, nullptr, midb, nullptr, nullptr, 0, nullptr, nullptr);
    // h_out = hin2 + g_m * (mid@mlp2^T + b)   64x32 tiles
    float* hout = (l == NL_-1) ? (float*)d_out : h;
    k_gemm_bf<64,32><<<dim3(16,16), 256, 0, stream>>>(midb, wM2 + (size_t)l*512*2048,
        mlp_b2 + (size_t)l*512, NT_, 512, 2048, 4, hout, nullptr, hin2,
        modl + 5*512, 6144, nullptr, nullptr);
  }
}

// Round 10
// 332.571 us; speedup vs baseline: 1.1319x; 1.0116x over previous
//
#include <hip/hip_runtime.h>
#include <hip/hip_bf16.h>
#include <math.h>

#define B_  2
#define L_  512
#define D_  512
#define H_  16
#define P_  128
#define NL_ 2
#define DH_ 32
#define FF_ 2048
#define NT_ (B_*L_)

typedef __bf16 bf16_t;
typedef bf16_t bf16x8 __attribute__((ext_vector_type(8)));
typedef bf16_t bf16x4 __attribute__((ext_vector_type(4)));
typedef bf16_t bf16x2 __attribute__((ext_vector_type(2)));
typedef float  f32x4  __attribute__((ext_vector_type(4)));

__device__ __forceinline__ float siluf(float x){ return x / (1.f + __expf(-x)); }
__device__ __forceinline__ float geluf(float x){
  const float c = 0.7978845608028654f;  // sqrt(2/pi)
  float x3 = x*x*x;
  return 0.5f*x*(1.f + tanhf(c*(x + 0.044715f*x3)));
}

__device__ __forceinline__ void gload16(const bf16_t* g, bf16_t* l){
  __builtin_amdgcn_global_load_lds(
      (const __attribute__((address_space(1))) unsigned int*)g,
      (__attribute__((address_space(3))) unsigned int*)l, 16, 0, 0);
}

template<int N> __device__ __forceinline__ void wait_vm(){
  if constexpr (N == 3)      asm volatile("s_waitcnt vmcnt(3)" ::: "memory");
  else if constexpr (N == 4) asm volatile("s_waitcnt vmcnt(4)" ::: "memory");
  else if constexpr (N == 6) asm volatile("s_waitcnt vmcnt(6)" ::: "memory");
  else                       asm volatile("s_waitcnt vmcnt(0)" ::: "memory");
}

// ---------------- merged preamble: cvtw (9216 blocks) | posemb (1024) | pfb2 (2048) ----------------
#define NB_CVT 9216
#define NB_POS 1024
__global__ __launch_bounds__(256) void k_pre(
      const float* __restrict__ s0, const float* __restrict__ s1,
      const float* __restrict__ s2, const float* __restrict__ s3,
      const float* __restrict__ s4, bf16_t* __restrict__ wdst,
      const float* __restrict__ pos, const float* __restrict__ posw,
      const int* __restrict__ maskp, float* __restrict__ h, float* __restrict__ keepf,
      const float* __restrict__ pair, const float* __restrict__ pfw,
      bf16_t* __restrict__ pfb, float* __restrict__ colm){
  __shared__ float sw[16][128];
  int bid = blockIdx.x;
  int tid = threadIdx.x;
  if (bid < NB_CVT){
    const size_t c0=3145728, c1=4718592, c2=5242880, c3=7340032, c4=9437184;
    size_t e = ((size_t)bid*256 + tid)*4;
    if (e >= c4) return;
    const float* s; size_t off;
    if      (e < c0){ s=s0; off=e; }
    else if (e < c1){ s=s1; off=e-c0; }
    else if (e < c2){ s=s2; off=e-c1; }
    else if (e < c3){ s=s3; off=e-c2; }
    else            { s=s4; off=e-c3; }
    float4 v = *(const float4*)(s + off);
    bf16x4 o; o[0]=(bf16_t)v.x; o[1]=(bf16_t)v.y; o[2]=(bf16_t)v.z; o[3]=(bf16_t)v.w;
    *(bf16x4*)(wdst + e) = o;
    return;
  }
  if (bid < NB_CVT + NB_POS){
    int n = bid - NB_CVT;                     // b*L + l
    float kf = (maskp[n] != 0) ? 0.f : 1.f;   // True = pad
    if (tid == 0) keepf[n] = kf;
    float p0 = pos[n*3+0], p1 = pos[n*3+1], p2 = pos[n*3+2];
    for (int d = tid; d < D_; d += 256){
      float v = p0*posw[d*3+0] + p1*posw[d*3+1] + p2*posw[d*3+2];
      h[(size_t)n*D_ + d] = kf*v;
    }
    return;
  }
  // pair bias fused with col-mean
  int blk = bid - NB_CVT - NB_POS;
  int mc = blk & 1;            // m half (256 each)
  int n  = blk >> 1;           // b*L + l
  int b = n >> 9, l = n & 511;
  {
    float4* swv = (float4*)&sw[0][0];
    const float4* wv = (const float4*)pfw;
    swv[tid] = wv[tid];
    swv[tid + 256] = wv[tid + 256];
  }
  __syncthreads();
  int m = mc*256 + tid;
  const float* rowp = pair + (((size_t)n)*512 + m)*128;
  float acc[16] = {};
  #pragma unroll 4
  for (int pc = 0; pc < 32; ++pc){
    float4 v = ((const float4*)rowp)[pc];
    v.x = siluf(v.x); v.y = siluf(v.y); v.z = siluf(v.z); v.w = siluf(v.w);
    #pragma unroll
    for (int hh = 0; hh < 16; ++hh){
      float4 wv = *(const float4*)&sw[hh][pc*4];   // wave-uniform broadcast
      acc[hh] += v.x*wv.x + v.y*wv.y + v.z*wv.z + v.w*wv.w;
    }
  }
  float mean = 0.f;
  #pragma unroll
  for (int hh = 0; hh < 16; ++hh) mean += acc[hh];
  colm[((size_t)n)*512 + m] = mean * (1.f/16.f);
  #pragma unroll
  for (int hh = 0; hh < 16; ++hh)
    pfb[(((size_t)(b*16 + hh))*512 + l)*512 + m] = (bf16_t)acc[hh];
}

// ---------------- top-3 rows per column + pair2node MLP + cond = silu(x + f2n) ----------------
__global__ __launch_bounds__(128) void k_topk_f2n(const float* __restrict__ colm,
      const float* __restrict__ pair, const float* __restrict__ keepf,
      const float* __restrict__ w1, const float* __restrict__ w2,
      const float* __restrict__ xin, bf16_t* __restrict__ cond){
  int n = blockIdx.x; int b = n >> 9, m = n & 511;
  __shared__ int sidx[3];
  __shared__ float f2n_s[128];
  __shared__ float u_s[128];
  int tid = threadIdx.x;
  if (tid < 64){
    const float* colbase = colm + ((size_t)b*512)*512 + m;   // stride 512 over l
    float v[8];
    #pragma unroll
    for (int i = 0; i < 8; ++i) v[i] = colbase[(size_t)(tid + 64*i)*512];
    int c0 = -1, c1 = -1;
    for (int r = 0; r < 3; ++r){
      float bv = -INFINITY; int bi = 1 << 30;
      #pragma unroll
      for (int i = 0; i < 8; ++i){
        int idx = tid + 64*i;
        bool excl = (idx == c0) || (idx == c1);
        float val = v[i];
        if (!excl && (val > bv || (val == bv && idx < bi))){ bv = val; bi = idx; }
      }
      for (int o = 32; o > 0; o >>= 1){
        float ov = __shfl_down(bv, o);
        int   oi = __shfl_down(bi, o);
        if (ov > bv || (ov == bv && oi < bi)){ bv = ov; bi = oi; }
      }
      bi = __shfl(bi, 0);
      if (tid == 0) sidx[r] = bi;
      if (r == 0) c0 = bi; else c1 = bi;
    }
  }
  __syncthreads();
  int i0 = sidx[0], i1 = sidx[1], i2 = sidx[2];
  float kc = keepf[n];
  float k0 = keepf[b*512 + i0], k1 = keepf[b*512 + i1], k2 = keepf[b*512 + i2];
  {
    int p = tid;
    float s = k0*pair[(((size_t)(b*512 + i0))*512 + m)*128 + p]
            + k1*pair[(((size_t)(b*512 + i1))*512 + m)*128 + p]
            + k2*pair[(((size_t)(b*512 + i2))*512 + m)*128 + p];
    f2n_s[p] = s * kc * (1.f/3.f);
  }
  __syncthreads();
  {
    int j = tid;
    const float4* wr4 = (const float4*)(w1 + (size_t)j*128);
    float acc = 0.f;
    #pragma unroll 8
    for (int pc = 0; pc < 32; ++pc){
      float4 wv = wr4[pc];
      float4 fv = *(const float4*)&f2n_s[pc*4];
      acc += fv.x*wv.x + fv.y*wv.y + fv.z*wv.z + fv.w*wv.w;
    }
    u_s[j] = siluf(acc);
  }
  __syncthreads();
  for (int d = tid; d < 512; d += 128){
    const float4* wr4 = (const float4*)(w2 + (size_t)d*128);
    float acc = 0.f;
    #pragma unroll 8
    for (int pc = 0; pc < 32; ++pc){
      float4 wv = wr4[pc];
      float4 uv = *(const float4*)&u_s[pc*4];
      acc += uv.x*wv.x + uv.y*wv.y + uv.z*wv.z + uv.w*wv.w;
    }
    float xv = xin[((size_t)(m*2 + b))*512 + d];     // x is [L,B,D]
    cond[(size_t)n*512 + d] = (bf16_t)siluf(xv + acc);
  }
}

// ---------------- LayerNorm(h [+ te]) * (1+sc) + sh -> bf16  (mod in bf16) ----------------
__global__ __launch_bounds__(128) void k_lnmod2(const float* __restrict__ hbase,
      const float* __restrict__ te, const bf16_t* __restrict__ mod,
      bf16_t* __restrict__ out, int sh_off, int sc_off, int mstride){
  int n = blockIdx.x; int b = n >> 9;
  int tid = threadIdx.x;
  float4 v = ((const float4*)(hbase + (size_t)n*512))[tid];
  if (te){
    float4 t = ((const float4*)(te + (size_t)b*512))[tid];
    v.x += t.x; v.y += t.y; v.z += t.z; v.w += t.w;
  }
  float s = v.x + v.y + v.z + v.w;
  float q = v.x*v.x + v.y*v.y + v.z*v.z + v.w*v.w;
  #pragma unroll
  for (int o = 1; o < 64; o <<= 1){ s += __shfl_xor(s, o); q += __shfl_xor(q, o); }
  __shared__ float s2[2], q2[2];
  if ((tid & 63) == 0){ s2[tid >> 6] = s; q2[tid >> 6] = q; }
  __syncthreads();
  float S = s2[0] + s2[1], Q = q2[0] + q2[1];
  float mean = S * (1.f/512.f);
  float var  = Q * (1.f/512.f) - mean*mean;
  float rstd = rsqrtf(var + 1e-5f);
  const bf16_t* mrow = mod + (size_t)n*mstride;
  bf16x4 sc = *(const bf16x4*)(mrow + sc_off + tid*4);
  bf16x4 sh = *(const bf16x4*)(mrow + sh_off + tid*4);
  bf16x4 rv;
  rv[0] = (bf16_t)((v.x - mean)*rstd*(1.f + (float)sc[0]) + (float)sh[0]);
  rv[1] = (bf16_t)((v.y - mean)*rstd*(1.f + (float)sc[1]) + (float)sh[1]);
  rv[2] = (bf16_t)((v.z - mean)*rstd*(1.f + (float)sc[2]) + (float)sh[2]);
  rv[3] = (bf16_t)((v.w - mean)*rstd*(1.f + (float)sc[3]) + (float)sh[3]);
  *(bf16x4*)(out + (size_t)n*512 + tid*4) = rv;
}

// ---------------- bf16 MFMA GEMM, 3-buffer ring + counted vmcnt (T3/T4 minimum) ----------------
// C[M,N] = epi(A[M,K] @ Bw[N,K]^T + bias)
// epi: 0 plain -> bf16 | 1 proj: outf = res + te + gate*v | 2 gelu->bf16
//      3 qkv->bf16 (+vT for V cols) | 4 mlp2: outf = res + gate*v
template<int BM, int BN>
__global__ __launch_bounds__(256) void k_gemm_bf(const bf16_t* __restrict__ A,
      const bf16_t* __restrict__ Bw, const float* __restrict__ bias,
      int M, int N, int K, int epi,
      float* __restrict__ outf, bf16_t* __restrict__ outb,
      const float* __restrict__ res, const bf16_t* __restrict__ gate, int gate_ld,
      const float* __restrict__ te, bf16_t* __restrict__ vT){
  const int FM = BM/32, FN = BN/32;
  const int CA = BM/32, CB = BN/32;      // 16B staging chunks per thread
  const int LPS = CA + CB;               // gload16 ops per stage per thread
  __shared__ __align__(16) bf16_t As[3*BM*64];
  __shared__ __align__(16) bf16_t Bs[3*BN*64];
  int tid = threadIdx.x;
  int m0 = blockIdx.y*BM, n0 = blockIdx.x*BN;
  int lane = tid & 63, wid = tid >> 6;
  int wr = wid >> 1, wc = wid & 1;
  int frow = lane & 15, g = lane >> 4;
  f32x4 acc[FM][FN] = {};

  auto stage = [&](int buf, int k0){
    int e = tid;
    #pragma unroll
    for (int i = 0; i < CA; ++i, e += 256){
      int row = e >> 3, cb = e & 7;
      gload16(A + (size_t)(m0+row)*K + k0 + ((cb ^ (row&7))<<3), &As[buf*BM*64 + e*8]);
    }
    e = tid;
    #pragma unroll
    for (int i = 0; i < CB; ++i, e += 256){
      int row = e >> 3, cb = e & 7;
      gload16(Bw + (size_t)(n0+row)*K + k0 + ((cb ^ (row&7))<<3), &Bs[buf*BN*64 + e*8]);
    }
  };
  auto compute = [&](int buf){
    #pragma unroll
    for (int ks = 0; ks < 2; ++ks){
      bf16x8 af[FM], bfv[FN];
      #pragma unroll
      for (int fm = 0; fm < FM; ++fm){
        int ar = wr*(BM/2) + fm*16 + frow;
        af[fm] = *(const bf16x8*)&As[buf*BM*64 + ar*64 + (((ks*4+g) ^ (ar&7))<<3)];
      }
      #pragma unroll
      for (int fn = 0; fn < FN; ++fn){
        int br = wc*(BN/2) + fn*16 + frow;
        bfv[fn] = *(const bf16x8*)&Bs[buf*BN*64 + br*64 + (((ks*4+g) ^ (br&7))<<3)];
      }
      #pragma unroll
      for (int fm = 0; fm < FM; ++fm)
        #pragma unroll
        for (int fn = 0; fn < FN; ++fn)
          acc[fm][fn] = __builtin_amdgcn_mfma_f32_16x16x32_bf16(af[fm], bfv[fn], acc[fm][fn], 0,0,0);
    }
  };

  int nst = K >> 6;
  stage(0, 0);
  if (nst > 1) stage(1, 64);
  wait_vm<LPS>();                          // buf0 done; stage1 may stay in flight
  __builtin_amdgcn_sched_barrier(0);
  __builtin_amdgcn_s_barrier();
  __builtin_amdgcn_sched_barrier(0);
  for (int k = 0; k < nst; ++k){
    if (k + 2 < nst) stage((k+2)%3, (k+2)*64);   // prefetch 2 ahead
    compute(k%3);
    asm volatile("s_waitcnt lgkmcnt(0)" ::: "memory");  // my ds_reads done before barrier
    wait_vm<LPS>();                         // oldest stage (next buf) landed; newest stays in flight
    __builtin_amdgcn_sched_barrier(0);
    __builtin_amdgcn_s_barrier();
    __builtin_amdgcn_sched_barrier(0);
  }

  #pragma unroll
  for (int fm = 0; fm < FM; ++fm){
    #pragma unroll
    for (int fn = 0; fn < FN; ++fn){
      int n = n0 + wc*(BN/2) + fn*16 + frow;
      float bb = bias[n];
      int row0 = m0 + wr*(BM/2) + fm*16 + g*4;
      if (epi == 3 && n >= 1024){
        int hh = (n-1024)>>5, dh = (n-1024)&31;
        int b = row0>>9, ll = row0&511;
        bf16x4 pv;
        #pragma unroll
        for (int i = 0; i < 4; ++i){
          float v = acc[fm][fn][i] + bb;
          outb[(size_t)(row0+i)*N + n] = (bf16_t)v;
          pv[i] = (bf16_t)v;
        }
        *(bf16x4*)&vT[(((size_t)(b*16+hh))*32 + dh)*512 + ll] = pv;
      } else {
        #pragma unroll
        for (int i = 0; i < 4; ++i){
          int row = row0 + i;
          float v = acc[fm][fn][i] + bb;
          if (epi == 1){
            v = res[(size_t)row*N + n] + te[(row>>9)*D_ + n]
              + (float)gate[(size_t)row*gate_ld + n]*v;
            outf[(size_t)row*N + n] = v;
          } else if (epi == 2){
            outb[(size_t)row*N + n] = (bf16_t)geluf(v);
          } else if (epi == 3){
            outb[(size_t)row*N + n] = (bf16_t)v;
          } else if (epi == 4){
            v = res[(size_t)row*N + n] + (float)gate[(size_t)row*gate_ld + n]*v;
            outf[(size_t)row*N + n] = v;
          } else {
            outb[(size_t)row*N + n] = (bf16_t)v;
          }
        }
      }
    }
  }
}

// ---------------- MFMA attention: block = (b,h,16-row q-tile) ----------------
__global__ __launch_bounds__(256) void k_attn2(const bf16_t* __restrict__ qkv,
      const bf16_t* __restrict__ vT, const bf16_t* __restrict__ pfb,
      const float* __restrict__ keepf, bf16_t* __restrict__ obuf){
  __shared__ float ss[16][516];
  __shared__ float opart[4][16][33];
  __shared__ float inv_s[16];
  int blk = blockIdx.x;
  int qt = blk & 31;
  int bh = blk >> 5;
  int b = bh >> 4, h = bh & 15;
  int r0 = qt*16;
  int tid = threadIdx.x;
  int lane = tid & 63, w = tid >> 6;
  int frow = lane & 15, g = lane >> 4;
  const float scale = 0.17677669529663687f;  // 1/sqrt(32)
  bf16x8 qf = *(const bf16x8*)(qkv + (size_t)(b*512 + r0 + frow)*1536 + h*32 + g*8);
  bf16x8 kf[8];
  #pragma unroll
  for (int t = 0; t < 8; ++t){
    int kc = w*128 + t*16;
    kf[t] = *(const bf16x8*)(qkv + (size_t)(b*512 + kc + frow)*1536 + 512 + h*32 + g*8);
  }
  #pragma unroll
  for (int t = 0; t < 8; ++t){
    int kc = w*128 + t*16;
    f32x4 s4 = {};
    s4 = __builtin_amdgcn_mfma_f32_16x16x32_bf16(kf[t], qf, s4, 0,0,0);
    int tok0 = kc + g*4;
    float4 kp = *(const float4*)&keepf[b*512 + tok0];
    bf16x4 pb = *(const bf16x4*)&pfb[((size_t)bh*512 + r0 + frow)*512 + tok0];
    float4 sv;
    sv.x = (kp.x == 0.f) ? -1e9f : s4[0]*scale + (float)pb[0];
    sv.y = (kp.y == 0.f) ? -1e9f : s4[1]*scale + (float)pb[1];
    sv.z = (kp.z == 0.f) ? -1e9f : s4[2]*scale + (float)pb[2];
    sv.w = (kp.w == 0.f) ? -1e9f : s4[3]*scale + (float)pb[3];
    *(float4*)&ss[frow][tok0] = sv;
  }
  bf16x8 vf[4][2];
  #pragma unroll
  for (int t = 0; t < 4; ++t){
    int kc = w*128 + t*32;
    #pragma unroll
    for (int fn = 0; fn < 2; ++fn)
      vf[t][fn] = *(const bf16x8*)(vT + ((size_t)bh*32 + fn*16 + frow)*512 + kc + g*8);
  }
  __syncthreads();
  {
    int r = tid >> 4, mo = tid & 15;
    float mx = -INFINITY;
    #pragma unroll 8
    for (int t2 = 0; t2 < 32; ++t2) mx = fmaxf(mx, ss[r][mo + 16*t2]);
    #pragma unroll
    for (int o = 1; o < 16; o <<= 1) mx = fmaxf(mx, __shfl_xor(mx, o));
    float sum = 0.f;
    #pragma unroll 8
    for (int t2 = 0; t2 < 32; ++t2){
      int m = mo + 16*t2;
      float e = __expf(ss[r][m] - mx);
      ss[r][m] = e;
      sum += e;
    }
    #pragma unroll
    for (int o = 1; o < 16; o <<= 1) sum += __shfl_xor(sum, o);
    if (mo == 0) inv_s[r] = 1.f/sum;
  }
  __syncthreads();
  f32x4 oacc[2] = {};
  #pragma unroll
  for (int t = 0; t < 4; ++t){
    int kc = w*128 + t*32;
    float4 p0 = *(const float4*)&ss[frow][kc + g*8];
    float4 p1 = *(const float4*)&ss[frow][kc + g*8 + 4];
    bf16x8 pfr;
    pfr[0]=(bf16_t)p0.x; pfr[1]=(bf16_t)p0.y; pfr[2]=(bf16_t)p0.z; pfr[3]=(bf16_t)p0.w;
    pfr[4]=(bf16_t)p1.x; pfr[5]=(bf16_t)p1.y; pfr[6]=(bf16_t)p1.z; pfr[7]=(bf16_t)p1.w;
    #pragma unroll
    for (int fn = 0; fn < 2; ++fn)
      oacc[fn] = __builtin_amdgcn_mfma_f32_16x16x32_bf16(pfr, vf[t][fn], oacc[fn], 0,0,0);
  }
  #pragma unroll
  for (int fn = 0; fn < 2; ++fn)
    #pragma unroll
    for (int i = 0; i < 4; ++i)
      opart[w][g*4+i][fn*16+frow] = oacc[fn][i];
  __syncthreads();
  {
    int q = tid >> 4, dh = (tid & 15)*2;
    float o0 = 0.f, o1 = 0.f;
    #pragma unroll
    for (int ww = 0; ww < 4; ++ww){ o0 += opart[ww][q][dh]; o1 += opart[ww][q][dh+1]; }
    float inv = inv_s[q];
    bf16x2 ov; ov[0] = (bf16_t)(o0*inv); ov[1] = (bf16_t)(o1*inv);
    *(bf16x2*)(obuf + (size_t)(b*512 + r0 + q)*512 + h*32 + dh) = ov;
  }
}

extern "C" void kernel_launch(void* const* d_in, const int* in_sizes, int n_in,
                              void* d_out, int out_size, void* d_ws, size_t ws_size,
                              hipStream_t stream){
  (void)in_sizes; (void)n_in; (void)out_size; (void)ws_size;
  const float* x        = (const float*)d_in[0];
  const float* pos      = (const float*)d_in[1];
  const float* time_emb = (const float*)d_in[2];
  const float* pair     = (const float*)d_in[3];
  const float* pos_w    = (const float*)d_in[4];
  const float* pfb_w    = (const float*)d_in[5];
  const float* p2n_w1   = (const float*)d_in[6];
  const float* p2n_w2   = (const float*)d_in[7];
  const float* adaln_w  = (const float*)d_in[8];
  const float* adaln_b  = (const float*)d_in[9];
  const float* qkv_w    = (const float*)d_in[10];
  const float* qkv_b    = (const float*)d_in[11];
  const float* proj_w   = (const float*)d_in[12];
  const float* proj_b   = (const float*)d_in[13];
  const float* mlp_w1   = (const float*)d_in[14];
  const float* mlp_b1   = (const float*)d_in[15];
  const float* mlp_w2   = (const float*)d_in[16];
  const float* mlp_b2   = (const float*)d_in[17];
  const int*   maskp    = (const int*)d_in[18];

  float* W = (float*)d_ws;
  size_t off = 0;
  auto alloc = [&](size_t nfw){ float* p = W + off; off += nfw; return p; };
  float*  h     = alloc(524288);
  float*  hin2  = alloc(524288);
  bf16_t* modb  = (bf16_t*)alloc(3145728);   // [1024][6144] bf16, both layers
  float*  colm  = alloc(524288);
  float*  keepf = alloc(1024);
  bf16_t* pfbb  = (bf16_t*)alloc(4194304);   // 8,388,608 bf16
  bf16_t* condb = (bf16_t*)alloc(262144);    // 524,288 bf16
  bf16_t* abuf  = (bf16_t*)alloc(262144);    // 524,288 bf16
  bf16_t* qkvb  = (bf16_t*)alloc(786432);    // 1,572,864 bf16
  bf16_t* vTb   = (bf16_t*)alloc(262144);    // 524,288 bf16
  bf16_t* midb  = (bf16_t*)alloc(1048576);   // 2,097,152 bf16
  bf16_t* obuf  = (bf16_t*)alloc(262144);    // 524,288 bf16
  bf16_t* wB    = (bf16_t*)alloc(4718592);   // 9,437,184 bf16
  bf16_t* wA  = wB;                 // [2][3072][512]
  bf16_t* wQ  = wB + 3145728;
  bf16_t* wP  = wB + 4718592;
  bf16_t* wM1 = wB + 5242880;
  bf16_t* wM2 = wB + 7340032;

  // merged preamble: weight-cvt | posemb | pair-bias+colmean
  k_pre<<<NB_CVT + NB_POS + NT_*2, 256, 0, stream>>>(
      adaln_w, qkv_w, proj_w, mlp_w1, mlp_w2, wB,
      pos, pos_w, maskp, h, keepf,
      pair, pfb_w, pfbb, colm);
  k_topk_f2n<<<NT_, 128, 0, stream>>>(colm, pair, keepf, p2n_w1, p2n_w2, x, condb);
  // batched adaLN for BOTH layers: modb[1024][6144](bf16) = cond @ [2·3072,512]^T + b  (64x64)
  k_gemm_bf<64,64><<<dim3(96,16), 256, 0, stream>>>(condb, wA, adaln_b,
      NT_, 6144, 512, 0, nullptr, modb, nullptr, nullptr, 0, nullptr, nullptr);

  for (int l = 0; l < NL_; ++l){
    const bf16_t* modl = modb + (size_t)l*3072;
    // a = LN(h+te)*(1+sc_a)+sh_a -> bf16
    k_lnmod2<<<NT_, 128, 0, stream>>>(h, time_emb, modl, abuf, 0, 512, 6144);
    // qkv -> bf16 (+ vT)   64x64 tiles
    k_gemm_bf<64,64><<<dim3(24,16), 256, 0, stream>>>(abuf, wQ + (size_t)l*1536*512,
        qkv_b + (size_t)l*1536, NT_, 1536, 512, 3, nullptr, qkvb, nullptr, nullptr, 0, nullptr, vTb);
    k_attn2<<<B_*H_*32, 256, 0, stream>>>(qkvb, vTb, pfbb, keepf, obuf);
    // hin2 = (h+te) + g_a * (o@proj^T + b)   64x32 tiles
    k_gemm_bf<64,32><<<dim3(16,16), 256, 0, stream>>>(obuf, wP + (size_t)l*512*512,
        proj_b + (size_t)l*512, NT_, 512, 512, 1, hin2, nullptr, h,
        modl + 2*512, 6144, time_emb, nullptr);
    k_lnmod2<<<NT_, 128, 0, stream>>>(hin2, nullptr, modl, abuf, 3*512, 4*512, 6144);
    // mlp1 gelu -> bf16   64x64 tiles
    k_gemm_bf<64,64><<<dim3(32,16), 256, 0, stream>>>(abuf, wM1 + (size_t)l*2048*512,
        mlp_b1 + (size_t)l*2048, NT_, 2048, 512, 2, nullptr, midb, nullptr, nullptr, 0, nullptr, nullptr);
    // h_out = hin2 + g_m * (mid@mlp2^T + b)   64x32 tiles
    float* hout = (l == NL_-1) ? (float*)d_out : h;
    k_gemm_bf<64,32><<<dim3(16,16), 256, 0, stream>>>(midb, wM2 + (size_t)l*512*2048,
        mlp_b2 + (size_t)l*512, NT_, 512, 2048, 4, hout, nullptr, hin2,
        modl + 5*512, 6144, nullptr, nullptr);
  }
}